// Round 1
// baseline (2355.207 us; speedup 1.0000x reference)
//
#include <hip/hip_runtime.h>
#include <hip/hip_bf16.h>

// Shapes: B=16, C=DIM=256, H=W=64, PATCH=16 (tokens N=256, pixels HW=4096)
// Restructure: out = conv3x3(e, W_eff[b]) + e, W_eff[b] = (proj @ softmax(q k^T /16)) @ v_w

#define NB 16
#define NC 256
#define NPIX 4096   // 64*64
#define NTOK 256    // 16*16

// ---------------- pool: e [b,c,64,64] -> maxe [b,c,16,16] (mean 4x4) ----------
__global__ void pool_k(const float* __restrict__ e, float* __restrict__ out) {
    int bc = blockIdx.x;                  // b*256 + c
    const float* p = e + (size_t)bc * NPIX;
    int t = threadIdx.x;                  // 256 threads: one per output pixel
    int py = t >> 4, px = t & 15;
    float s = 0.f;
#pragma unroll
    for (int r = 0; r < 4; ++r) {
        const float4 v = *(const float4*)(p + (py * 4 + r) * 64 + px * 4);
        s += v.x + v.y + v.z + v.w;
    }
    out[(size_t)bc * NTOK + t] = s * 0.0625f;
}

// ---- 3x3 conv on 16x16 planes + L2-normalize over the 256 tokens -------------
// in: [B,256,16,16], w: [256,256,9]; out: q layout [b,c,n] or kT layout [b,n,d]
__global__ void conv16_norm_k(const float* __restrict__ in, const float* __restrict__ w,
                              float* __restrict__ out, int transpose) {
    int bo = blockIdx.x;
    int b = bo >> 8, o = bo & 255;
    int t = threadIdx.x;
    int y = t >> 4, x = t & 15;
    __shared__ float wl[2304];
    __shared__ float pl[256];
    __shared__ float r4[4];
    const float* wrow = w + (size_t)o * 2304;
    for (int j = t; j < 2304; j += 256) wl[j] = wrow[j];
    const float* inp = in + (size_t)b * NC * NTOK;
    float acc = 0.f;
    for (int i = 0; i < NC; ++i) {
        __syncthreads();
        pl[t] = inp[i * NTOK + t];
        __syncthreads();
        const float* wi = wl + i * 9;
#pragma unroll
        for (int ky = 0; ky < 3; ++ky) {
            int yy = y + ky - 1;
            if (yy < 0 || yy > 15) continue;
#pragma unroll
            for (int kx = 0; kx < 3; ++kx) {
                int xx = x + kx - 1;
                if (xx < 0 || xx > 15) continue;
                acc += pl[yy * 16 + xx] * wi[ky * 3 + kx];
            }
        }
    }
    // block-wide sum of squares (4 waves of 64)
    float sq = acc * acc;
#pragma unroll
    for (int off = 32; off; off >>= 1) sq += __shfl_xor(sq, off, 64);
    if ((t & 63) == 0) r4[t >> 6] = sq;
    __syncthreads();
    float tot = r4[0] + r4[1] + r4[2] + r4[3];
    float rn = 1.0f / fmaxf(sqrtf(tot), 1e-12f);
    float val = acc * rn;
    if (transpose) out[(size_t)b * 65536 + (size_t)t * 256 + o] = val;   // kT[b,n,d]
    else           out[(size_t)b * 65536 + (size_t)o * 256 + t] = val;   // q[b,c,n]
}

// ---- attn[b,c,d] = softmax_d( q[b,c,:]·k[b,d,:] / 16 ) -----------------------
__global__ void attn_k(const float* __restrict__ q, const float* __restrict__ kT,
                       float* __restrict__ attn) {
    int bc = blockIdx.x;
    int b = bc >> 8;
    int d = threadIdx.x;
    __shared__ float ql[256];
    __shared__ float r4[4];
    ql[d] = q[(size_t)bc * 256 + d];
    __syncthreads();
    const float* kp = kT + (size_t)b * 65536;
    float acc = 0.f;
    for (int n = 0; n < 256; ++n) acc += ql[n] * kp[n * 256 + d];
    acc *= 0.0625f;  // 1/sqrt(256)
    // block softmax over d
    float m = acc;
#pragma unroll
    for (int off = 32; off; off >>= 1) m = fmaxf(m, __shfl_xor(m, off, 64));
    if ((d & 63) == 0) r4[d >> 6] = m;
    __syncthreads();
    m = fmaxf(fmaxf(r4[0], r4[1]), fmaxf(r4[2], r4[3]));
    float ex = __expf(acc - m);
    float s = ex;
#pragma unroll
    for (int off = 32; off; off >>= 1) s += __shfl_xor(s, off, 64);
    __syncthreads();
    if ((d & 63) == 0) r4[d >> 6] = s;
    __syncthreads();
    s = r4[0] + r4[1] + r4[2] + r4[3];
    attn[(size_t)bc * 256 + d] = ex / s;
}

// ---- M[b,o,d] = sum_c proj[o,c] * attn[b,c,d] --------------------------------
__global__ void mproj_k(const float* __restrict__ proj, const float* __restrict__ attn,
                        float* __restrict__ M) {
    int bo = blockIdx.x;
    int b = bo >> 8, o = bo & 255;
    int d = threadIdx.x;
    __shared__ float pl[256];
    pl[d] = proj[o * 256 + d];
    __syncthreads();
    const float* ap = attn + (size_t)b * 65536;
    float acc = 0.f;
    for (int c = 0; c < 256; ++c) acc += pl[c] * ap[c * 256 + d];
    M[(size_t)bo * 256 + d] = acc;
}

// ---- W_eff[b,o,i,9] = sum_d M[b,o,d] * v_w[d,i,9] ----------------------------
__global__ void weff_k(const float* __restrict__ M, const float* __restrict__ vw,
                       float* __restrict__ weff) {
    int blk = blockIdx.x;
    int b = blk >> 6, og = blk & 63;   // 4 output channels per block
    int t = threadIdx.x;
    __shared__ float ml[4][256];
    for (int j = t; j < 1024; j += 256)
        ml[j >> 8][j & 255] = M[(size_t)b * 65536 + (size_t)(og * 4 + (j >> 8)) * 256 + (j & 255)];
    __syncthreads();
    float acc[4][9];
#pragma unroll
    for (int oo = 0; oo < 4; ++oo)
#pragma unroll
        for (int j = 0; j < 9; ++j) acc[oo][j] = 0.f;
    for (int d = 0; d < 256; ++d) {
        const float* vr = vw + (size_t)d * 2304 + t * 9;
        float wv[9];
#pragma unroll
        for (int j = 0; j < 9; ++j) wv[j] = vr[j];
#pragma unroll
        for (int oo = 0; oo < 4; ++oo) {
            float mm = ml[oo][d];
#pragma unroll
            for (int j = 0; j < 9; ++j) acc[oo][j] += mm * wv[j];
        }
    }
#pragma unroll
    for (int oo = 0; oo < 4; ++oo) {
        float* wo = weff + (size_t)b * (256 * 2304) + (size_t)(og * 4 + oo) * 2304 + t * 9;
#pragma unroll
        for (int j = 0; j < 9; ++j) wo[j] = acc[oo][j];
    }
}

// ---- big conv: out[b,o,:,:] = conv3x3(e[b], W_eff[b,o]) + e[b,o,:,:] ---------
__global__ void __launch_bounds__(256) bigconv_k(const float* __restrict__ e,
                                                 const float* __restrict__ weff,
                                                 float* __restrict__ out) {
    int blk = blockIdx.x;
    int b = blk >> 6, og = blk & 63;   // 4 output channels per block
    int t = threadIdx.x;
    __shared__ float wl[4 * 2304];     // 36.9 KB
    __shared__ float pl[64 * 65];      // 16.6 KB padded plane
    for (int j = t; j < 9216; j += 256)
        wl[j] = weff[(size_t)b * (256 * 2304) + (size_t)og * 4 * 2304 + j];
    int ty = t >> 4, tx = t & 15;
    int r0 = ty * 4, c0 = tx * 4;      // 4x4 pixel tile per thread
    float acc[4][16];
#pragma unroll
    for (int oo = 0; oo < 4; ++oo)
#pragma unroll
        for (int j = 0; j < 16; ++j) acc[oo][j] = 0.f;
    const float* ep = e + (size_t)b * NC * NPIX;
    for (int i = 0; i < NC; ++i) {
        __syncthreads();
        const float4* src = (const float4*)(ep + (size_t)i * NPIX);
#pragma unroll
        for (int j = 0; j < 4; ++j) {
            float4 v = src[j * 256 + t];
            int idx = (j * 256 + t) * 4;
            int row = idx >> 6, col = idx & 63;
            float* dst = &pl[row * 65 + col];
            dst[0] = v.x; dst[1] = v.y; dst[2] = v.z; dst[3] = v.w;
        }
        __syncthreads();
        float xr[6][6];
#pragma unroll
        for (int rr = 0; rr < 6; ++rr) {
            int r = r0 + rr - 1;
#pragma unroll
            for (int cc = 0; cc < 6; ++cc) {
                int c = c0 + cc - 1;
                xr[rr][cc] = (r >= 0 && r < 64 && c >= 0 && c < 64) ? pl[r * 65 + c] : 0.f;
            }
        }
#pragma unroll
        for (int oo = 0; oo < 4; ++oo) {
            const float* wi = &wl[oo * 2304 + i * 9];
            float w0 = wi[0], w1 = wi[1], w2 = wi[2], w3 = wi[3], w4 = wi[4],
                  w5 = wi[5], w6 = wi[6], w7 = wi[7], w8 = wi[8];
#pragma unroll
            for (int rr = 0; rr < 4; ++rr) {
#pragma unroll
                for (int cc = 0; cc < 4; ++cc) {
                    acc[oo][rr * 4 + cc] += xr[rr][cc] * w0 + xr[rr][cc + 1] * w1 + xr[rr][cc + 2] * w2
                                          + xr[rr + 1][cc] * w3 + xr[rr + 1][cc + 1] * w4 + xr[rr + 1][cc + 2] * w5
                                          + xr[rr + 2][cc] * w6 + xr[rr + 2][cc + 1] * w7 + xr[rr + 2][cc + 2] * w8;
                }
            }
        }
    }
    // epilogue: + residual e[b,o], write out
#pragma unroll
    for (int oo = 0; oo < 4; ++oo) {
        int o = og * 4 + oo;
        float* op = out + (size_t)b * NC * NPIX + (size_t)o * NPIX;
        const float* er = ep + (size_t)o * NPIX;
#pragma unroll
        for (int rr = 0; rr < 4; ++rr) {
            int row = r0 + rr;
#pragma unroll
            for (int cc = 0; cc < 4; ++cc) {
                int idx = row * 64 + c0 + cc;
                op[idx] = acc[oo][rr * 4 + cc] + er[idx];
            }
        }
    }
}

extern "C" void kernel_launch(void* const* d_in, const int* in_sizes, int n_in,
                              void* d_out, int out_size, void* d_ws, size_t ws_size,
                              hipStream_t stream) {
    const float* e    = (const float*)d_in[0];   // [16,256,64,64]
    const float* pam  = (const float*)d_in[1];   // [16,256,16,16]
    const float* qw   = (const float*)d_in[2];   // [256,256,3,3]
    const float* kw   = (const float*)d_in[3];
    const float* vw   = (const float*)d_in[4];
    const float* pw   = (const float*)d_in[5];   // [256,256,1,1]
    float* out = (float*)d_out;
    float* ws  = (float*)d_ws;

    float* maxe = ws;                 // 1,048,576 f32
    float* qb   = ws + 1048576;       // 1,048,576
    float* kT   = ws + 2097152;       // 1,048,576
    float* attn = ws + 3145728;       // 1,048,576
    float* Mb   = ws + 4194304;       // 1,048,576
    float* weff = ws + 5242880;       // 9,437,184  (total ~58.7 MB)

    pool_k<<<NB * NC, 256, 0, stream>>>(e, maxe);
    conv16_norm_k<<<NB * NC, 256, 0, stream>>>(maxe, qw, qb, 0);
    conv16_norm_k<<<NB * NC, 256, 0, stream>>>(pam, kw, kT, 1);
    attn_k<<<NB * NC, 256, 0, stream>>>(qb, kT, attn);
    mproj_k<<<NB * NC, 256, 0, stream>>>(pw, attn, Mb);
    weff_k<<<NB * 64, 256, 0, stream>>>(Mb, vw, weff);
    bigconv_k<<<NB * 64, 256, 0, stream>>>(e, weff, out);
}

// Round 2
// 886.868 us; speedup vs baseline: 2.6556x; 2.6556x over previous
//
#include <hip/hip_runtime.h>
#include <hip/hip_bf16.h>

#define NB 16
#define NC 256
#define NPIX 4096
#define NTOK 256

typedef __attribute__((ext_vector_type(8))) short short8;
typedef __attribute__((ext_vector_type(4))) float f32x4;

static __device__ __forceinline__ ushort f2bf(float f) {
    __hip_bfloat16 h = __float2bfloat16(f);
    return *(ushort*)&h;
}

// ---------------- pool: e [b,c,64,64] -> maxe [b,c,16,16] (mean 4x4) ----------
__global__ void pool_k(const float* __restrict__ e, float* __restrict__ out) {
    int bc = blockIdx.x;
    const float* p = e + (size_t)bc * NPIX;
    int t = threadIdx.x;
    int py = t >> 4, px = t & 15;
    float s = 0.f;
#pragma unroll
    for (int r = 0; r < 4; ++r) {
        const float4 v = *(const float4*)(p + (py * 4 + r) * 64 + px * 4);
        s += v.x + v.y + v.z + v.w;
    }
    out[(size_t)bc * NTOK + t] = s * 0.0625f;
}

// ---- 3x3 conv on 16x16 planes + L2-normalize, 4 outputs per block ------------
__global__ void __launch_bounds__(256) conv16n4_k(const float* __restrict__ in,
                                                  const float* __restrict__ w,
                                                  float* __restrict__ out, int transpose) {
    int blk = blockIdx.x;
    int b = blk >> 6, og = blk & 63, o0 = og * 4;
    int t = threadIdx.x;
    int y = t >> 4, x = t & 15;
    __shared__ float wl[4][2304];
    __shared__ float pls[32][256];
    __shared__ float r4[4];
    const float* wrow = w + (size_t)o0 * 2304;
    for (int j = t; j < 9216; j += 256) wl[j / 2304][j % 2304] = wrow[j];
    // precompute 3x3 neighborhood offsets + validity (same for all channels)
    int noff[9]; bool nok[9];
#pragma unroll
    for (int ky = 0; ky < 3; ++ky)
#pragma unroll
        for (int kx = 0; kx < 3; ++kx) {
            int yy = y + ky - 1, xx = x + kx - 1;
            int k = ky * 3 + kx;
            nok[k] = (yy >= 0 && yy < 16 && xx >= 0 && xx < 16);
            noff[k] = (yy & 15) * 16 + (xx & 15);
        }
    const float* inp = in + (size_t)b * 65536;
    float acc[4] = {0.f, 0.f, 0.f, 0.f};
    for (int c0 = 0; c0 < 256; c0 += 32) {
        __syncthreads();
        const float4* src = (const float4*)(inp + c0 * 256);
        for (int j = t; j < 2048; j += 256) ((float4*)pls)[j] = src[j];
        __syncthreads();
        for (int ii = 0; ii < 32; ++ii) {
            const float* P = pls[ii];
            float v[9];
#pragma unroll
            for (int k = 0; k < 9; ++k) v[k] = nok[k] ? P[noff[k]] : 0.f;
            int i = c0 + ii;
#pragma unroll
            for (int oo = 0; oo < 4; ++oo) {
                const float* wi = &wl[oo][i * 9];
                float a = acc[oo];
                a += v[0]*wi[0] + v[1]*wi[1] + v[2]*wi[2]
                   + v[3]*wi[3] + v[4]*wi[4] + v[5]*wi[5]
                   + v[6]*wi[6] + v[7]*wi[7] + v[8]*wi[8];
                acc[oo] = a;
            }
        }
    }
    float rn[4];
#pragma unroll
    for (int oo = 0; oo < 4; ++oo) {
        float sq = acc[oo] * acc[oo];
#pragma unroll
        for (int off = 32; off; off >>= 1) sq += __shfl_xor(sq, off, 64);
        __syncthreads();
        if ((t & 63) == 0) r4[t >> 6] = sq;
        __syncthreads();
        float tot = r4[0] + r4[1] + r4[2] + r4[3];
        rn[oo] = 1.0f / fmaxf(sqrtf(tot), 1e-12f);
    }
#pragma unroll
    for (int oo = 0; oo < 4; ++oo) {
        float val = acc[oo] * rn[oo];
        int o = o0 + oo;
        if (transpose) out[(size_t)b * 65536 + (size_t)t * 256 + o] = val;
        else           out[(size_t)b * 65536 + (size_t)o * 256 + t] = val;
    }
}

// ---- attn[b,c,d] = softmax_d( q[b,c,:]·k[b,d,:] / 16 ) -----------------------
__global__ void attn_k(const float* __restrict__ q, const float* __restrict__ kT,
                       float* __restrict__ attn) {
    int bc = blockIdx.x;
    int b = bc >> 8;
    int d = threadIdx.x;
    __shared__ float ql[256];
    __shared__ float r4[4];
    ql[d] = q[(size_t)bc * 256 + d];
    __syncthreads();
    const float* kp = kT + (size_t)b * 65536;
    float acc = 0.f;
    for (int n = 0; n < 256; ++n) acc += ql[n] * kp[n * 256 + d];
    acc *= 0.0625f;
    float m = acc;
#pragma unroll
    for (int off = 32; off; off >>= 1) m = fmaxf(m, __shfl_xor(m, off, 64));
    if ((d & 63) == 0) r4[d >> 6] = m;
    __syncthreads();
    m = fmaxf(fmaxf(r4[0], r4[1]), fmaxf(r4[2], r4[3]));
    float ex = __expf(acc - m);
    float s = ex;
#pragma unroll
    for (int off = 32; off; off >>= 1) s += __shfl_xor(s, off, 64);
    __syncthreads();
    if ((d & 63) == 0) r4[d >> 6] = s;
    __syncthreads();
    s = r4[0] + r4[1] + r4[2] + r4[3];
    attn[(size_t)bc * 256 + d] = ex / s;
}

// ---- Mbf[b,o,d] = bf16( sum_c proj[o,c] * attn[b,c,d] ) ----------------------
__global__ void mproj_k(const float* __restrict__ proj, const float* __restrict__ attn,
                        ushort* __restrict__ Mbf) {
    int bo = blockIdx.x;
    int b = bo >> 8, o = bo & 255;
    int d = threadIdx.x;
    __shared__ float pl[256];
    pl[d] = proj[o * 256 + d];
    __syncthreads();
    const float* ap = attn + (size_t)b * 65536;
    float acc = 0.f;
    for (int c = 0; c < 256; ++c) acc += pl[c] * ap[c * 256 + d];
    Mbf[(size_t)bo * 256 + d] = f2bf(acc);
}

// ---- vwT[j*256+i][d] = bf16(vw[d][i*9+j])  (B-operand for weff GEMM) ---------
__global__ void vwt_k(const float* __restrict__ vw, ushort* __restrict__ vwT) {
    int blk = blockIdx.x;            // 36 blocks: 9 j x 4 d-chunks
    int j = blk >> 2, d0 = (blk & 3) * 64;
    int t = threadIdx.x;             // i
    ushort* dst = vwT + ((size_t)(j * 256 + t)) * 256 + d0;
#pragma unroll
    for (int g = 0; g < 8; ++g) {
        short8 v;
#pragma unroll
        for (int m = 0; m < 8; ++m)
            v[m] = (short)f2bf(vw[(size_t)(d0 + g * 8 + m) * 2304 + t * 9 + j]);
        *(short8*)(dst + g * 8) = v;
    }
}

// ---- wbf[b][j][o][i] = bf16( sum_d Mbf[b,o,d] * vw[d,i,j] )  via MFMA --------
__global__ void __launch_bounds__(512) weff_mfma(const ushort* __restrict__ Mbf,
                                                 const ushort* __restrict__ vwT,
                                                 ushort* __restrict__ wbf) {
    int blk = blockIdx.x;            // 144 blocks: 16 b x 9 j
    int b = blk / 9, j = blk % 9;
    int tid = threadIdx.x;
    int wid = tid >> 6, lane = tid & 63;
    int wm = wid >> 1, wn = wid & 1;     // 4 x 2 wave grid: M=64/wave, N=128/wave
    int khalf = lane >> 4, l16 = lane & 15;
    f32x4 acc[4][8];
#pragma unroll
    for (int mf = 0; mf < 4; ++mf)
#pragma unroll
        for (int nf = 0; nf < 8; ++nf) acc[mf][nf] = (f32x4){0.f, 0.f, 0.f, 0.f};
    const ushort* abase = Mbf + (size_t)b * 65536 + (size_t)(wm * 64 + l16) * 256 + khalf * 8;
    const ushort* bbase = vwT + (size_t)(j * 256 + wn * 128 + l16) * 256 + khalf * 8;
    for (int kc = 0; kc < 8; ++kc) {
        int d0 = kc * 32;
        short8 af[4], bfr[8];
#pragma unroll
        for (int mf = 0; mf < 4; ++mf) af[mf] = *(const short8*)(abase + mf * 16 * 256 + d0);
#pragma unroll
        for (int nf = 0; nf < 8; ++nf) bfr[nf] = *(const short8*)(bbase + nf * 16 * 256 + d0);
#pragma unroll
        for (int mf = 0; mf < 4; ++mf)
#pragma unroll
            for (int nf = 0; nf < 8; ++nf)
                acc[mf][nf] = __builtin_amdgcn_mfma_f32_16x16x32_bf16(af[mf], bfr[nf], acc[mf][nf], 0, 0, 0);
    }
    ushort* wout = wbf + ((size_t)(b * 9 + j)) * 65536;
#pragma unroll
    for (int mf = 0; mf < 4; ++mf) {
        int o = wm * 64 + mf * 16 + khalf * 4;
#pragma unroll
        for (int nf = 0; nf < 8; ++nf) {
            int ic = wn * 128 + nf * 16 + l16;
#pragma unroll
            for (int r = 0; r < 4; ++r)
                wout[(size_t)(o + r) * 256 + ic] = f2bf(acc[mf][nf][r]);
        }
    }
}

// ---- NHWC bf16 transform: et[b][y][x][c] = bf16(e[b][c][y][x]) ---------------
__global__ void __launch_bounds__(256) nhwc_k(const float* __restrict__ e,
                                              ushort* __restrict__ et) {
    int blk = blockIdx.x;            // 1024 blocks: b*64 + y
    int b = blk >> 6, y = blk & 63;
    int t = threadIdx.x;
    __shared__ float lt[256][64];    // XOR-swizzled: col = x ^ ((c>>3)&31)
    const float* ep = e + (size_t)b * NC * NPIX + y * 64;
    {
        int x4 = (t & 15) * 4;
        for (int rr = 0; rr < 16; ++rr) {
            int c = rr * 16 + (t >> 4);
            float4 v = *(const float4*)(ep + (size_t)c * NPIX + x4);
            int s = (c >> 3) & 31;
            lt[c][(x4 + 0) ^ s] = v.x;
            lt[c][(x4 + 1) ^ s] = v.y;
            lt[c][(x4 + 2) ^ s] = v.z;
            lt[c][(x4 + 3) ^ s] = v.w;
        }
    }
    __syncthreads();
    {
        int l = t & 31, c0 = l * 8;
        ushort* op = et + ((size_t)(b * 64 + y) * 64) * 256;
        for (int r = 0; r < 8; ++r) {
            int x = r * 8 + (t >> 5);
            short8 v;
#pragma unroll
            for (int k = 0; k < 8; ++k) v[k] = (short)f2bf(lt[c0 + k][x ^ l]);
            *(short8*)(op + (size_t)x * 256 + c0) = v;
        }
    }
}

// ---- big conv via MFMA: out[b,o,p] = sum_tap sum_i W[o,i,tap]*e_sh + e[b,o,p]
__global__ void __launch_bounds__(512) bigconv_mfma(const ushort* __restrict__ et,
                                                    const ushort* __restrict__ wbf,
                                                    const float* __restrict__ e,
                                                    float* __restrict__ out) {
    int blk = blockIdx.x;            // 512 blocks: 16 b x 32 pixel-tiles(128 px)
    int b = blk >> 5, pt = blk & 31;
    int tid = threadIdx.x;
    int wid = tid >> 6, lane = tid & 63;
    int wm = wid >> 1, wn = wid & 1;     // 4 x 2: M=64/wave, N=64/wave
    int khalf = lane >> 4, l16 = lane & 15;
    f32x4 acc[4][4];
#pragma unroll
    for (int mf = 0; mf < 4; ++mf)
#pragma unroll
        for (int nf = 0; nf < 4; ++nf) acc[mf][nf] = (f32x4){0.f, 0.f, 0.f, 0.f};
    const ushort* etb = et + (size_t)b * 64 * 64 * 256;
    const ushort* wb = wbf + (size_t)b * 9 * 65536;
    int pcol0 = pt * 128 + wn * 64 + l16;
    const short8 zfrag = {};
    for (int koff = 0; koff < 9; ++koff) {
        int dy = koff / 3 - 1, dx = koff % 3 - 1;
        const ushort* bbase[4];
        bool bval[4];
#pragma unroll
        for (int nf = 0; nf < 4; ++nf) {
            int p = pcol0 + nf * 16;
            int yy = (p >> 6) + dy, xx = (p & 63) + dx;
            bval[nf] = (yy >= 0 && yy < 64 && xx >= 0 && xx < 64);
            int yyc = min(max(yy, 0), 63), xxc = min(max(xx, 0), 63);
            bbase[nf] = etb + ((size_t)(yyc * 64 + xxc) << 8) + khalf * 8;
        }
        const ushort* abase = wb + (size_t)koff * 65536 + (size_t)(wm * 64 + l16) * 256 + khalf * 8;
        for (int kc = 0; kc < 8; ++kc) {
            int i0 = kc * 32;
            short8 af[4], bfr[4];
#pragma unroll
            for (int mf = 0; mf < 4; ++mf) af[mf] = *(const short8*)(abase + mf * 16 * 256 + i0);
#pragma unroll
            for (int nf = 0; nf < 4; ++nf) bfr[nf] = bval[nf] ? *(const short8*)(bbase[nf] + i0) : zfrag;
#pragma unroll
            for (int mf = 0; mf < 4; ++mf)
#pragma unroll
                for (int nf = 0; nf < 4; ++nf)
                    acc[mf][nf] = __builtin_amdgcn_mfma_f32_16x16x32_bf16(af[mf], bfr[nf], acc[mf][nf], 0, 0, 0);
        }
    }
    const float* eb = e + (size_t)b * NC * NPIX;
    float* ob = out + (size_t)b * NC * NPIX;
#pragma unroll
    for (int mf = 0; mf < 4; ++mf) {
        int o = wm * 64 + mf * 16 + khalf * 4;
#pragma unroll
        for (int nf = 0; nf < 4; ++nf) {
            int p = pcol0 + nf * 16;
#pragma unroll
            for (int r = 0; r < 4; ++r) {
                size_t idx = (size_t)(o + r) * NPIX + p;
                ob[idx] = acc[mf][nf][r] + eb[idx];
            }
        }
    }
}

extern "C" void kernel_launch(void* const* d_in, const int* in_sizes, int n_in,
                              void* d_out, int out_size, void* d_ws, size_t ws_size,
                              hipStream_t stream) {
    const float* e   = (const float*)d_in[0];
    const float* pam = (const float*)d_in[1];
    const float* qw  = (const float*)d_in[2];
    const float* kw  = (const float*)d_in[3];
    const float* vw  = (const float*)d_in[4];
    const float* pw  = (const float*)d_in[5];
    float* out = (float*)d_out;
    float* ws  = (float*)d_ws;

    // buffer plan (f32 offsets); lifetimes allow reuse:
    float*  maxe = ws;                       // 1M f32; dead after conv16(q)
    float*  qb   = ws + 1048576;             // 1M f32; dead after attn
    float*  kT   = ws + 2097152;             // 1M f32; dead after attn
    float*  attn = maxe;                     // reuse maxe region
    ushort* Mbf  = (ushort*)qb;              // 1M ushort (2MB) in qb region
    ushort* vwT  = (ushort*)kT;              // 589824 ushort in kT region
    ushort* wbf  = (ushort*)(ws + 3145728);  // 9,437,184 ushort (18.9MB)
    ushort* et   = (ushort*)(ws + 7864320);  // 16,777,216 ushort (33.5MB)

    pool_k<<<NB * NC, 256, 0, stream>>>(e, maxe);
    conv16n4_k<<<NB * 64, 256, 0, stream>>>(maxe, qw, qb, 0);
    conv16n4_k<<<NB * 64, 256, 0, stream>>>(pam, kw, kT, 1);
    attn_k<<<NB * NC, 256, 0, stream>>>(qb, kT, attn);
    mproj_k<<<NB * NC, 256, 0, stream>>>(pw, attn, Mbf);
    vwt_k<<<36, 256, 0, stream>>>(vw, vwT);
    weff_mfma<<<NB * 9, 512, 0, stream>>>(Mbf, vwT, wbf);
    nhwc_k<<<NB * 64, 256, 0, stream>>>(e, et);
    bigconv_mfma<<<NB * 32, 512, 0, stream>>>(et, wbf, e, out);
}

// Round 3
// 688.183 us; speedup vs baseline: 3.4224x; 1.2887x over previous
//
#include <hip/hip_runtime.h>
#include <hip/hip_bf16.h>

#define NB 16
#define NC 256
#define NPIX 4096
#define NTOK 256

typedef __attribute__((ext_vector_type(8))) short short8;
typedef __attribute__((ext_vector_type(4))) float f32x4;

static __device__ __forceinline__ ushort f2bf(float f) {
    __hip_bfloat16 h = __float2bfloat16(f);
    return *(ushort*)&h;
}
static __device__ __forceinline__ float bf2f(ushort u) {
    union { unsigned int i; float f; } cv; cv.i = ((unsigned int)u) << 16; return cv.f;
}

// ---- pool e -> maxeT[b][tok][c] bf16 (mean 4x4 + transpose) ------------------
__global__ void __launch_bounds__(256) pooltr_k(const float* __restrict__ e,
                                                ushort* __restrict__ maxeT) {
    int blk = blockIdx.x;                // 256 blocks: b*16 + cg
    int b = blk >> 4, cg = blk & 15;
    int t = threadIdx.x;                 // token
    int py = t >> 4, px = t & 15;
    __shared__ float lt[16][256];
#pragma unroll
    for (int cc = 0; cc < 16; ++cc) {
        int c = cg * 16 + cc;
        const float* p = e + (size_t)(b * 256 + c) * NPIX;
        float s = 0.f;
#pragma unroll
        for (int r = 0; r < 4; ++r) {
            float4 v = *(const float4*)(p + (py * 4 + r) * 64 + px * 4);
            s += v.x + v.y + v.z + v.w;
        }
        lt[cc][t] = s * 0.0625f;
    }
    __syncthreads();
    ushort* dst = maxeT + (size_t)b * 65536 + (size_t)t * 256 + cg * 16;
#pragma unroll
    for (int g = 0; g < 2; ++g) {
        short8 v;
#pragma unroll
        for (int k = 0; k < 8; ++k) v[k] = (short)f2bf(lt[g * 8 + k][t]);
        *(short8*)(dst + g * 8) = v;
    }
}

// ---- pam [b][c][256] -> pamT[b][tok][c] bf16 ---------------------------------
__global__ void __launch_bounds__(256) pamtr_k(const float* __restrict__ pam,
                                               ushort* __restrict__ pamT) {
    int blk = blockIdx.x;                // 256 blocks: b*16 + cg
    int b = blk >> 4, cg = blk & 15;
    int t = threadIdx.x;
    __shared__ float lt[16][256];
#pragma unroll
    for (int cc = 0; cc < 16; ++cc)
        lt[cc][t] = pam[(size_t)(b * 256 + cg * 16 + cc) * 256 + t];
    __syncthreads();
    ushort* dst = pamT + (size_t)b * 65536 + (size_t)t * 256 + cg * 16;
#pragma unroll
    for (int g = 0; g < 2; ++g) {
        short8 v;
#pragma unroll
        for (int k = 0; k < 8; ++k) v[k] = (short)f2bf(lt[g * 8 + k][t]);
        *(short8*)(dst + g * 8) = v;
    }
}

// ---- w [o][i*9+tap] f32 -> wt[tap][o][i] bf16 (for qw and kw) ----------------
__global__ void __launch_bounds__(256) wtap_k(const float* __restrict__ qw,
                                              const float* __restrict__ kw,
                                              ushort* __restrict__ wqT,
                                              ushort* __restrict__ wkT) {
    int blk = blockIdx.x;                // 512: first 256 = q, next = k
    const float* src = (blk < 256) ? qw : kw;
    ushort* dst = (blk < 256) ? wqT : wkT;
    int o = blk & 255;
    int i = threadIdx.x;
    float wv[9];
#pragma unroll
    for (int j = 0; j < 9; ++j) wv[j] = src[(size_t)o * 2304 + i * 9 + j];
#pragma unroll
    for (int j = 0; j < 9; ++j) dst[(size_t)j * 65536 + (size_t)o * 256 + i] = f2bf(wv[j]);
}

// ---- conv16 via MFMA + L2 norm: out = normalize(conv3x3(inT, wt)) ------------
// inT: [b][tok][c] bf16, wt: [9][o][i] bf16; out bf16: q [b][o][n] or kT [b][n][o]
__global__ void __launch_bounds__(512) conv16_mfma(const ushort* __restrict__ inT,
                                                   const ushort* __restrict__ wt,
                                                   ushort* __restrict__ outp,
                                                   int transpose) {
    int blk = blockIdx.x;                // 64 blocks: b*4 + oquad
    int b = blk >> 2, o0 = (blk & 3) * 64;
    int tid = threadIdx.x;
    int wid = tid >> 6, lane = tid & 63;
    int wm = wid >> 1, wn = wid & 1;     // wave: rows [wm*16,+16), cols [wn*128,+128)
    int khalf = lane >> 4, l16 = lane & 15;
    f32x4 acc[8];
#pragma unroll
    for (int nf = 0; nf < 8; ++nf) acc[nf] = (f32x4){0.f, 0.f, 0.f, 0.f};
    const ushort* itb = inT + (size_t)b * 65536;
    const short8 zfrag = {};
    for (int tap = 0; tap < 9; ++tap) {
        int dy = tap / 3 - 1, dx = tap % 3 - 1;
        const ushort* bbase[8]; bool bval[8];
#pragma unroll
        for (int nf = 0; nf < 8; ++nf) {
            int n = wn * 128 + nf * 16 + l16;
            int yy = (n >> 4) + dy, xx = (n & 15) + dx;
            bval[nf] = (yy >= 0 && yy < 16 && xx >= 0 && xx < 16);
            int nn = ((yy & 15) << 4) | (xx & 15);
            bbase[nf] = itb + (size_t)nn * 256 + khalf * 8;
        }
        const ushort* abase = wt + (size_t)tap * 65536 + (size_t)(o0 + wm * 16 + l16) * 256 + khalf * 8;
        for (int kc = 0; kc < 8; ++kc) {
            short8 af = *(const short8*)(abase + kc * 32);
#pragma unroll
            for (int nf = 0; nf < 8; ++nf) {
                short8 bf = bval[nf] ? *(const short8*)(bbase[nf] + kc * 32) : zfrag;
                acc[nf] = __builtin_amdgcn_mfma_f32_16x16x32_bf16(af, bf, acc[nf], 0, 0, 0);
            }
        }
    }
    // row L2 norm: sum acc^2 over cols; reduce over l16 lanes then across wn
    __shared__ float nrm[64][2];
    float ss[4] = {0.f, 0.f, 0.f, 0.f};
#pragma unroll
    for (int nf = 0; nf < 8; ++nf)
#pragma unroll
        for (int r = 0; r < 4; ++r) ss[r] += acc[nf][r] * acc[nf][r];
#pragma unroll
    for (int r = 0; r < 4; ++r) {
#pragma unroll
        for (int off = 1; off < 16; off <<= 1) ss[r] += __shfl_xor(ss[r], off, 64);
    }
    if (l16 == 0) {
#pragma unroll
        for (int r = 0; r < 4; ++r) nrm[wm * 16 + khalf * 4 + r][wn] = ss[r];
    }
    __syncthreads();
    float rn[4];
#pragma unroll
    for (int r = 0; r < 4; ++r) {
        int row = wm * 16 + khalf * 4 + r;
        float tot = nrm[row][0] + nrm[row][1];
        rn[r] = 1.0f / fmaxf(sqrtf(tot), 1e-12f);
    }
    ushort* ob = outp + (size_t)b * 65536;
#pragma unroll
    for (int nf = 0; nf < 8; ++nf) {
        int col = wn * 128 + nf * 16 + l16;
#pragma unroll
        for (int r = 0; r < 4; ++r) {
            int row = o0 + wm * 16 + khalf * 4 + r;
            ushort v = f2bf(acc[nf][r] * rn[r]);
            if (transpose) ob[(size_t)col * 256 + row] = v;
            else           ob[(size_t)row * 256 + col] = v;
        }
    }
}

// ---- attn[b,c,d] = softmax_d( q[b,c,:]·k[b,d,:] / 16 ), bf16 inputs ----------
__global__ void attn_k(const ushort* __restrict__ q, const ushort* __restrict__ kT,
                       float* __restrict__ attn) {
    int bc = blockIdx.x;
    int b = bc >> 8;
    int d = threadIdx.x;
    __shared__ float ql[256];
    __shared__ float r4[4];
    ql[d] = bf2f(q[(size_t)bc * 256 + d]);
    __syncthreads();
    const ushort* kp = kT + (size_t)b * 65536;
    float acc = 0.f;
    for (int n = 0; n < 256; ++n) acc += ql[n] * bf2f(kp[n * 256 + d]);
    acc *= 0.0625f;
    float m = acc;
#pragma unroll
    for (int off = 32; off; off >>= 1) m = fmaxf(m, __shfl_xor(m, off, 64));
    if ((d & 63) == 0) r4[d >> 6] = m;
    __syncthreads();
    m = fmaxf(fmaxf(r4[0], r4[1]), fmaxf(r4[2], r4[3]));
    float ex = __expf(acc - m);
    float s = ex;
#pragma unroll
    for (int off = 32; off; off >>= 1) s += __shfl_xor(s, off, 64);
    __syncthreads();
    if ((d & 63) == 0) r4[d >> 6] = s;
    __syncthreads();
    s = r4[0] + r4[1] + r4[2] + r4[3];
    attn[(size_t)bc * 256 + d] = ex / s;
}

// ---- Mbf[b,o,d] = bf16( sum_c proj[o,c] * attn[b,c,d] ) ----------------------
__global__ void mproj_k(const float* __restrict__ proj, const float* __restrict__ attn,
                        ushort* __restrict__ Mbf) {
    int bo = blockIdx.x;
    int b = bo >> 8, o = bo & 255;
    int d = threadIdx.x;
    __shared__ float pl[256];
    pl[d] = proj[o * 256 + d];
    __syncthreads();
    const float* ap = attn + (size_t)b * 65536;
    float acc = 0.f;
    for (int c = 0; c < 256; ++c) acc += pl[c] * ap[c * 256 + d];
    Mbf[(size_t)bo * 256 + d] = f2bf(acc);
}

// ---- vwT[j*256+i][d] = bf16(vw[d][i*9+j]) ------------------------------------
__global__ void vwt_k(const float* __restrict__ vw, ushort* __restrict__ vwT) {
    int blk = blockIdx.x;            // 36 blocks: 9 j x 4 d-chunks
    int j = blk >> 2, d0 = (blk & 3) * 64;
    int t = threadIdx.x;             // i
    ushort* dst = vwT + ((size_t)(j * 256 + t)) * 256 + d0;
#pragma unroll
    for (int g = 0; g < 8; ++g) {
        short8 v;
#pragma unroll
        for (int m = 0; m < 8; ++m)
            v[m] = (short)f2bf(vw[(size_t)(d0 + g * 8 + m) * 2304 + t * 9 + j]);
        *(short8*)(dst + g * 8) = v;
    }
}

// ---- wbf[b][j][o][i] = bf16( sum_d Mbf[b,o,d] * vw[d,i,j] ) via MFMA ---------
__global__ void __launch_bounds__(512) weff_mfma(const ushort* __restrict__ Mbf,
                                                 const ushort* __restrict__ vwT,
                                                 ushort* __restrict__ wbf) {
    int blk = blockIdx.x;            // 144 blocks: 16 b x 9 j
    int b = blk / 9, j = blk % 9;
    int tid = threadIdx.x;
    int wid = tid >> 6, lane = tid & 63;
    int wm = wid >> 1, wn = wid & 1;
    int khalf = lane >> 4, l16 = lane & 15;
    f32x4 acc[4][8];
#pragma unroll
    for (int mf = 0; mf < 4; ++mf)
#pragma unroll
        for (int nf = 0; nf < 8; ++nf) acc[mf][nf] = (f32x4){0.f, 0.f, 0.f, 0.f};
    const ushort* abase = Mbf + (size_t)b * 65536 + (size_t)(wm * 64 + l16) * 256 + khalf * 8;
    const ushort* bbase = vwT + (size_t)(j * 256 + wn * 128 + l16) * 256 + khalf * 8;
    for (int kc = 0; kc < 8; ++kc) {
        int d0 = kc * 32;
        short8 af[4], bfr[8];
#pragma unroll
        for (int mf = 0; mf < 4; ++mf) af[mf] = *(const short8*)(abase + mf * 16 * 256 + d0);
#pragma unroll
        for (int nf = 0; nf < 8; ++nf) bfr[nf] = *(const short8*)(bbase + nf * 16 * 256 + d0);
#pragma unroll
        for (int mf = 0; mf < 4; ++mf)
#pragma unroll
            for (int nf = 0; nf < 8; ++nf)
                acc[mf][nf] = __builtin_amdgcn_mfma_f32_16x16x32_bf16(af[mf], bfr[nf], acc[mf][nf], 0, 0, 0);
    }
    ushort* wout = wbf + ((size_t)(b * 9 + j)) * 65536;
#pragma unroll
    for (int mf = 0; mf < 4; ++mf) {
        int o = wm * 64 + mf * 16 + khalf * 4;
#pragma unroll
        for (int nf = 0; nf < 8; ++nf) {
            int ic = wn * 128 + nf * 16 + l16;
#pragma unroll
            for (int r = 0; r < 4; ++r)
                wout[(size_t)(o + r) * 256 + ic] = f2bf(acc[mf][nf][r]);
        }
    }
}

// ---- NHWC bf16 transform: et[b][y][x][c] = bf16(e[b][c][y][x]) ---------------
__global__ void __launch_bounds__(256) nhwc_k(const float* __restrict__ e,
                                              ushort* __restrict__ et) {
    int blk = blockIdx.x;            // 1024 blocks: b*64 + y
    int b = blk >> 6, y = blk & 63;
    int t = threadIdx.x;
    __shared__ float lt[256][64];    // XOR-swizzled: col = x ^ ((c>>3)&31)
    const float* ep = e + (size_t)b * NC * NPIX + y * 64;
    {
        int x4 = (t & 15) * 4;
        for (int rr = 0; rr < 16; ++rr) {
            int c = rr * 16 + (t >> 4);
            float4 v = *(const float4*)(ep + (size_t)c * NPIX + x4);
            int s = (c >> 3) & 31;
            lt[c][(x4 + 0) ^ s] = v.x;
            lt[c][(x4 + 1) ^ s] = v.y;
            lt[c][(x4 + 2) ^ s] = v.z;
            lt[c][(x4 + 3) ^ s] = v.w;
        }
    }
    __syncthreads();
    {
        int l = t & 31, c0 = l * 8;
        ushort* op = et + ((size_t)(b * 64 + y) * 64) * 256;
        for (int r = 0; r < 8; ++r) {
            int x = r * 8 + (t >> 5);
            short8 v;
#pragma unroll
            for (int k = 0; k < 8; ++k) v[k] = (short)f2bf(lt[c0 + k][x ^ l]);
            *(short8*)(op + (size_t)x * 256 + c0) = v;
        }
    }
}

// ---- big conv via MFMA + residual --------------------------------------------
__global__ void __launch_bounds__(512) bigconv_mfma(const ushort* __restrict__ et,
                                                    const ushort* __restrict__ wbf,
                                                    const float* __restrict__ e,
                                                    float* __restrict__ out) {
    int blk = blockIdx.x;            // 512 blocks: 16 b x 32 pixel-tiles(128 px)
    int b = blk >> 5, pt = blk & 31;
    int tid = threadIdx.x;
    int wid = tid >> 6, lane = tid & 63;
    int wm = wid >> 1, wn = wid & 1;
    int khalf = lane >> 4, l16 = lane & 15;
    f32x4 acc[4][4];
#pragma unroll
    for (int mf = 0; mf < 4; ++mf)
#pragma unroll
        for (int nf = 0; nf < 4; ++nf) acc[mf][nf] = (f32x4){0.f, 0.f, 0.f, 0.f};
    const ushort* etb = et + (size_t)b * 64 * 64 * 256;
    const ushort* wb = wbf + (size_t)b * 9 * 65536;
    int pcol0 = pt * 128 + wn * 64 + l16;
    const short8 zfrag = {};
    for (int koff = 0; koff < 9; ++koff) {
        int dy = koff / 3 - 1, dx = koff % 3 - 1;
        const ushort* bbase[4];
        bool bval[4];
#pragma unroll
        for (int nf = 0; nf < 4; ++nf) {
            int p = pcol0 + nf * 16;
            int yy = (p >> 6) + dy, xx = (p & 63) + dx;
            bval[nf] = (yy >= 0 && yy < 64 && xx >= 0 && xx < 64);
            int yyc = min(max(yy, 0), 63), xxc = min(max(xx, 0), 63);
            bbase[nf] = etb + ((size_t)(yyc * 64 + xxc) << 8) + khalf * 8;
        }
        const ushort* abase = wb + (size_t)koff * 65536 + (size_t)(wm * 64 + l16) * 256 + khalf * 8;
        for (int kc = 0; kc < 8; ++kc) {
            int i0 = kc * 32;
            short8 af[4], bfr[4];
#pragma unroll
            for (int mf = 0; mf < 4; ++mf) af[mf] = *(const short8*)(abase + mf * 16 * 256 + i0);
#pragma unroll
            for (int nf = 0; nf < 4; ++nf) bfr[nf] = bval[nf] ? *(const short8*)(bbase[nf] + i0) : zfrag;
#pragma unroll
            for (int mf = 0; mf < 4; ++mf)
#pragma unroll
                for (int nf = 0; nf < 4; ++nf)
                    acc[mf][nf] = __builtin_amdgcn_mfma_f32_16x16x32_bf16(af[mf], bfr[nf], acc[mf][nf], 0, 0, 0);
        }
    }
    const float* eb = e + (size_t)b * NC * NPIX;
    float* ob = out + (size_t)b * NC * NPIX;
#pragma unroll
    for (int mf = 0; mf < 4; ++mf) {
        int o = wm * 64 + mf * 16 + khalf * 4;
#pragma unroll
        for (int nf = 0; nf < 4; ++nf) {
            int p = pcol0 + nf * 16;
#pragma unroll
            for (int r = 0; r < 4; ++r) {
                size_t idx = (size_t)(o + r) * NPIX + p;
                ob[idx] = acc[mf][nf][r] + eb[idx];
            }
        }
    }
}

extern "C" void kernel_launch(void* const* d_in, const int* in_sizes, int n_in,
                              void* d_out, int out_size, void* d_ws, size_t ws_size,
                              hipStream_t stream) {
    const float* e   = (const float*)d_in[0];
    const float* pam = (const float*)d_in[1];
    const float* qw  = (const float*)d_in[2];
    const float* kw  = (const float*)d_in[3];
    const float* vw  = (const float*)d_in[4];
    const float* pw  = (const float*)d_in[5];
    float* out = (float*)d_out;
    float* ws  = (float*)d_ws;

    // persistent big buffers first (f32-slot offsets):
    ushort* wbf  = (ushort*)ws;                    // [0, 4718592) f32-slots (18.9MB)
    ushort* et   = (ushort*)(ws + 4718592);        // [4718592, 13107200) (33.5MB)
    float*  S    = ws + 13107200;                  // small-buffer region
    ushort* maxeT = (ushort*)S;                    // [S+0, S+524288)
    ushort* pamT  = (ushort*)(S + 524288);         // [S+524288, S+1048576)
    ushort* wqT   = (ushort*)(S + 1048576);        // 294912 slots
    ushort* wkT   = (ushort*)(S + 1343488);        // 294912 slots
    ushort* qb    = (ushort*)(S + 1638400);        // 524288 slots
    ushort* kTb   = (ushort*)(S + 2162688);        // 524288 slots -> end S+2686976 (63.2MB total)
    float*  attn  = S;                             // reuse maxeT+pamT (dead)
    ushort* Mbf   = (ushort*)(S + 1048576);        // reuse wqT+wkT (dead)
    ushort* vwT   = (ushort*)(S + 1638400);        // reuse qb (dead after attn)

    pooltr_k<<<NB * 16, 256, 0, stream>>>(e, maxeT);
    pamtr_k<<<NB * 16, 256, 0, stream>>>(pam, pamT);
    wtap_k<<<512, 256, 0, stream>>>(qw, kw, wqT, wkT);
    conv16_mfma<<<NB * 4, 512, 0, stream>>>(maxeT, wqT, qb, 0);
    conv16_mfma<<<NB * 4, 512, 0, stream>>>(pamT, wkT, kTb, 1);
    attn_k<<<NB * NC, 256, 0, stream>>>(qb, kTb, attn);
    mproj_k<<<NB * NC, 256, 0, stream>>>(pw, attn, Mbf);
    vwt_k<<<36, 256, 0, stream>>>(vw, vwT);
    weff_mfma<<<NB * 9, 512, 0, stream>>>(Mbf, vwT, wbf);
    nhwc_k<<<NB * 64, 256, 0, stream>>>(e, et);
    bigconv_mfma<<<NB * 32, 512, 0, stream>>>(et, wbf, e, out);
}

// Round 4
// 452.939 us; speedup vs baseline: 5.1998x; 1.5194x over previous
//
#include <hip/hip_runtime.h>
#include <hip/hip_bf16.h>

#define NB 16
#define NC 256
#define NPIX 4096

typedef __attribute__((ext_vector_type(8))) short short8;
typedef __attribute__((ext_vector_type(4))) short short4v;
typedef __attribute__((ext_vector_type(4))) float f32x4;

static __device__ __forceinline__ ushort f2bf(float f) {
    __hip_bfloat16 h = __float2bfloat16(f);
    return *(ushort*)&h;
}

// ================= prep: all input-only transforms in one launch ==============
// blocks: [0,256) pooltr | [256,512) pamtr | [512,1024) wtap q/k |
//         [1024,1040) projcast | [1040,1104) vw transpose | [1104,2128) nhwc
__global__ void __launch_bounds__(256) prep_k(
    const float* __restrict__ e, const float* __restrict__ pam,
    const float* __restrict__ qw, const float* __restrict__ kw,
    const float* __restrict__ vw, const float* __restrict__ pw,
    ushort* __restrict__ maxeT, ushort* __restrict__ pamT,
    ushort* __restrict__ wqT, ushort* __restrict__ wkT,
    ushort* __restrict__ pbf, ushort* __restrict__ vwT,
    ushort* __restrict__ et) {
    __shared__ float smem[16384];   // 64KB shared by all branches
    int blk = blockIdx.x, t = threadIdx.x;
    if (blk < 512) {
        // pool(e)->maxeT[b][tok][c] bf16  /  pam->pamT[b][tok][c] bf16
        int isPam = blk >> 8;
        int bb = blk & 255;
        int b = bb >> 4, cg = bb & 15;
        float (*lt)[256] = (float(*)[256])smem;
        if (!isPam) {
            int py = t >> 4, px = t & 15;
#pragma unroll
            for (int cc = 0; cc < 16; ++cc) {
                int c = cg * 16 + cc;
                const float* p = e + (size_t)(b * 256 + c) * NPIX;
                float s = 0.f;
#pragma unroll
                for (int r = 0; r < 4; ++r) {
                    float4 v = *(const float4*)(p + (py * 4 + r) * 64 + px * 4);
                    s += v.x + v.y + v.z + v.w;
                }
                lt[cc][t] = s * 0.0625f;
            }
        } else {
#pragma unroll
            for (int cc = 0; cc < 16; ++cc)
                lt[cc][t] = pam[(size_t)(b * 256 + cg * 16 + cc) * 256 + t];
        }
        __syncthreads();
        ushort* dstb = (isPam ? pamT : maxeT) + (size_t)b * 65536 + (size_t)t * 256 + cg * 16;
#pragma unroll
        for (int g = 0; g < 2; ++g) {
            short8 v;
#pragma unroll
            for (int k = 0; k < 8; ++k) v[k] = (short)f2bf(lt[g * 8 + k][t]);
            *(short8*)(dstb + g * 8) = v;
        }
    } else if (blk < 1024) {
        // wtap: w[o][i*9+j] f32 -> wt[j][o][i] bf16
        int idx = blk - 512;
        const float* src = (idx < 256) ? qw : kw;
        ushort* dst = (idx < 256) ? wqT : wkT;
        int o = idx & 255;
        float wv[9];
#pragma unroll
        for (int j = 0; j < 9; ++j) wv[j] = src[(size_t)o * 2304 + t * 9 + j];
#pragma unroll
        for (int j = 0; j < 9; ++j) dst[(size_t)j * 65536 + (size_t)o * 256 + t] = f2bf(wv[j]);
    } else if (blk < 1040) {
        // projcast: pw f32 -> pbf bf16 (row-major [o][c])
        int base = (blk - 1024) * 4096;
        for (int g = 0; g < 16; ++g) {
            int idx = base + g * 256 + t;
            pbf[idx] = f2bf(pw[idx]);
        }
    } else if (blk < 1104) {
        // vw transpose: vwT[j][i][d] = bf16(vw[d][i*9+j]), d-chunk of 4
        int d0 = (blk - 1040) * 4;
        float* lt = smem;   // flat [4][2304]
        for (int u = 0; u < 36; ++u) lt[u * 256 + t] = vw[(size_t)d0 * 2304 + u * 256 + t];
        __syncthreads();
#pragma unroll
        for (int r = 0; r < 9; ++r) {
            int idx = r * 256 + t;
            int i = idx / 9, j = idx % 9;
            short4v v;
#pragma unroll
            for (int dd = 0; dd < 4; ++dd) v[dd] = (short)f2bf(lt[dd * 2304 + idx]);
            *(short4v*)(vwT + ((size_t)(j * 256 + i)) * 256 + d0) = v;
        }
    } else {
        // nhwc: et[b][y][x][c] = bf16(e[b][c][y][x]); XCD-matched b mapping
        int local = blk - 1104;
        int ii = local >> 3;
        int b = (local & 7) + 8 * (ii >> 6);
        int y = ii & 63;
        float (*lt)[64] = (float(*)[64])smem;   // [256][64], XOR-swizzled cols
        const float* ep = e + (size_t)b * NC * NPIX + y * 64;
        {
            int x4 = (t & 15) * 4;
            for (int rr = 0; rr < 16; ++rr) {
                int c = rr * 16 + (t >> 4);
                float4 v = *(const float4*)(ep + (size_t)c * NPIX + x4);
                int s = (c >> 3) & 31;
                lt[c][(x4 + 0) ^ s] = v.x;
                lt[c][(x4 + 1) ^ s] = v.y;
                lt[c][(x4 + 2) ^ s] = v.z;
                lt[c][(x4 + 3) ^ s] = v.w;
            }
        }
        __syncthreads();
        {
            int l = t & 31, c0 = l * 8;
            ushort* op = et + ((size_t)(b * 64 + y) * 64) * 256;
            for (int r = 0; r < 8; ++r) {
                int x = r * 8 + (t >> 5);
                short8 v;
#pragma unroll
                for (int k = 0; k < 8; ++k) v[k] = (short)f2bf(lt[c0 + k][x ^ l]);
                *(short8*)(op + (size_t)x * 256 + c0) = v;
            }
        }
    }
}

// ---- conv16 via MFMA + L2 norm; q (blk<64) and k halves in one launch --------
// out layout [b][o][n] bf16 (row = channel, col = token) for both
__global__ void __launch_bounds__(512) conv16_mfma(const ushort* __restrict__ maxeT,
                                                   const ushort* __restrict__ pamT,
                                                   const ushort* __restrict__ wqT,
                                                   const ushort* __restrict__ wkT,
                                                   ushort* __restrict__ qb,
                                                   ushort* __restrict__ kTb) {
    int blk = blockIdx.x;
    const ushort* inT = (blk < 64) ? maxeT : pamT;
    const ushort* wt  = (blk < 64) ? wqT : wkT;
    ushort* outp      = (blk < 64) ? qb : kTb;
    int bb = blk & 63;
    int b = bb >> 2, o0 = (bb & 3) * 64;
    int tid = threadIdx.x;
    int wid = tid >> 6, lane = tid & 63;
    int wm = wid >> 1, wn = wid & 1;     // rows [wm*16,+16), cols [wn*128,+128)
    int kq = lane >> 4, l16 = lane & 15;
    f32x4 acc[8];
#pragma unroll
    for (int nf = 0; nf < 8; ++nf) acc[nf] = (f32x4){0.f, 0.f, 0.f, 0.f};
    const ushort* itb = inT + (size_t)b * 65536;
    const short8 zfrag = {};
    for (int tap = 0; tap < 9; ++tap) {
        int dy = tap / 3 - 1, dx = tap % 3 - 1;
        const ushort* bbase[8]; bool bval[8];
#pragma unroll
        for (int nf = 0; nf < 8; ++nf) {
            int n = wn * 128 + nf * 16 + l16;
            int yy = (n >> 4) + dy, xx = (n & 15) + dx;
            bval[nf] = (yy >= 0 && yy < 16 && xx >= 0 && xx < 16);
            int nn = ((yy & 15) << 4) | (xx & 15);
            bbase[nf] = itb + (size_t)nn * 256 + kq * 8;
        }
        const ushort* abase = wt + (size_t)tap * 65536 + (size_t)(o0 + wm * 16 + l16) * 256 + kq * 8;
        for (int kc = 0; kc < 8; ++kc) {
            short8 af = *(const short8*)(abase + kc * 32);
#pragma unroll
            for (int nf = 0; nf < 8; ++nf) {
                short8 bf = bval[nf] ? *(const short8*)(bbase[nf] + kc * 32) : zfrag;
                acc[nf] = __builtin_amdgcn_mfma_f32_16x16x32_bf16(af, bf, acc[nf], 0, 0, 0);
            }
        }
    }
    __shared__ float nrm[64][2];
    float ss[4] = {0.f, 0.f, 0.f, 0.f};
#pragma unroll
    for (int nf = 0; nf < 8; ++nf)
#pragma unroll
        for (int r = 0; r < 4; ++r) ss[r] += acc[nf][r] * acc[nf][r];
#pragma unroll
    for (int r = 0; r < 4; ++r) {
#pragma unroll
        for (int off = 1; off < 16; off <<= 1) ss[r] += __shfl_xor(ss[r], off, 64);
    }
    if (l16 == 0) {
#pragma unroll
        for (int r = 0; r < 4; ++r) nrm[wm * 16 + kq * 4 + r][wn] = ss[r];
    }
    __syncthreads();
    float rn[4];
#pragma unroll
    for (int r = 0; r < 4; ++r) {
        int row = wm * 16 + kq * 4 + r;
        float tot = nrm[row][0] + nrm[row][1];
        rn[r] = 1.0f / fmaxf(sqrtf(tot), 1e-12f);
    }
    ushort* ob = outp + (size_t)b * 65536;
#pragma unroll
    for (int nf = 0; nf < 8; ++nf) {
        int col = wn * 128 + nf * 16 + l16;
#pragma unroll
        for (int r = 0; r < 4; ++r) {
            int row = o0 + wm * 16 + kq * 4 + r;
            ob[(size_t)row * 256 + col] = f2bf(acc[nf][r] * rn[r]);
        }
    }
}

// ---- attn via MFMA + in-fragment softmax; writes attnT[d][c] bf16 ------------
__global__ void __launch_bounds__(512) attn_mfma(const ushort* __restrict__ qb,
                                                 const ushort* __restrict__ kTb,
                                                 ushort* __restrict__ attnT) {
    int b = blockIdx.x;
    int tid = threadIdx.x, wid = tid >> 6, lane = tid & 63;
    int kq = lane >> 4, l16 = lane & 15;
    int c0w = wid * 32;                  // wave's 32 rows (c)
    f32x4 acc[2][16];
#pragma unroll
    for (int mf = 0; mf < 2; ++mf)
#pragma unroll
        for (int nf = 0; nf < 16; ++nf) acc[mf][nf] = (f32x4){0.f, 0.f, 0.f, 0.f};
    const ushort* qp = qb + (size_t)b * 65536;
    const ushort* kp = kTb + (size_t)b * 65536;
    for (int kc = 0; kc < 8; ++kc) {
        short8 af[2];
#pragma unroll
        for (int mf = 0; mf < 2; ++mf)
            af[mf] = *(const short8*)(qp + (size_t)(c0w + mf * 16 + l16) * 256 + kc * 32 + kq * 8);
#pragma unroll
        for (int nf = 0; nf < 16; ++nf) {
            short8 bf = *(const short8*)(kp + (size_t)(nf * 16 + l16) * 256 + kc * 32 + kq * 8);
#pragma unroll
            for (int mf = 0; mf < 2; ++mf)
                acc[mf][nf] = __builtin_amdgcn_mfma_f32_16x16x32_bf16(af[mf], bf, acc[mf][nf], 0, 0, 0);
        }
    }
    // scale + softmax over cols (d) per row
#pragma unroll
    for (int mf = 0; mf < 2; ++mf)
#pragma unroll
        for (int nf = 0; nf < 16; ++nf)
#pragma unroll
            for (int r = 0; r < 4; ++r) acc[mf][nf][r] *= 0.0625f;
#pragma unroll
    for (int mf = 0; mf < 2; ++mf)
#pragma unroll
        for (int r = 0; r < 4; ++r) {
            float m = -1e30f;
#pragma unroll
            for (int nf = 0; nf < 16; ++nf) m = fmaxf(m, acc[mf][nf][r]);
#pragma unroll
            for (int off = 1; off < 16; off <<= 1) m = fmaxf(m, __shfl_xor(m, off, 64));
            float s = 0.f;
#pragma unroll
            for (int nf = 0; nf < 16; ++nf) {
                float ex = __expf(acc[mf][nf][r] - m);
                acc[mf][nf][r] = ex;
                s += ex;
            }
#pragma unroll
            for (int off = 1; off < 16; off <<= 1) s += __shfl_xor(s, off, 64);
            float inv = 1.0f / s;
#pragma unroll
            for (int nf = 0; nf < 16; ++nf) acc[mf][nf][r] *= inv;
        }
    ushort* ap = attnT + (size_t)b * 65536;
#pragma unroll
    for (int mf = 0; mf < 2; ++mf) {
        int cb = c0w + mf * 16 + kq * 4;
#pragma unroll
        for (int nf = 0; nf < 16; ++nf) {
            int d = nf * 16 + l16;
            short4v v;
#pragma unroll
            for (int r = 0; r < 4; ++r) v[r] = (short)f2bf(acc[mf][nf][r]);
            *(short4v*)(ap + (size_t)d * 256 + cb) = v;
        }
    }
}

// ---- Mbf[b][o][d] = bf16( sum_c pbf[o,c] * attnT[d,c] ) via MFMA -------------
__global__ void __launch_bounds__(512) mproj_mfma(const ushort* __restrict__ pbf,
                                                  const ushort* __restrict__ attnT,
                                                  ushort* __restrict__ Mbf) {
    int b = blockIdx.x;
    int tid = threadIdx.x, wid = tid >> 6, lane = tid & 63;
    int kq = lane >> 4, l16 = lane & 15;
    int c0w = wid * 32;                  // wave's 32 rows (o)
    f32x4 acc[2][16];
#pragma unroll
    for (int mf = 0; mf < 2; ++mf)
#pragma unroll
        for (int nf = 0; nf < 16; ++nf) acc[mf][nf] = (f32x4){0.f, 0.f, 0.f, 0.f};
    const ushort* ap = attnT + (size_t)b * 65536;
    for (int kc = 0; kc < 8; ++kc) {
        short8 af[2];
#pragma unroll
        for (int mf = 0; mf < 2; ++mf)
            af[mf] = *(const short8*)(pbf + (size_t)(c0w + mf * 16 + l16) * 256 + kc * 32 + kq * 8);
#pragma unroll
        for (int nf = 0; nf < 16; ++nf) {
            short8 bf = *(const short8*)(ap + (size_t)(nf * 16 + l16) * 256 + kc * 32 + kq * 8);
#pragma unroll
            for (int mf = 0; mf < 2; ++mf)
                acc[mf][nf] = __builtin_amdgcn_mfma_f32_16x16x32_bf16(af[mf], bf, acc[mf][nf], 0, 0, 0);
        }
    }
    ushort* mb = Mbf + (size_t)b * 65536;
#pragma unroll
    for (int mf = 0; mf < 2; ++mf)
#pragma unroll
        for (int nf = 0; nf < 16; ++nf)
#pragma unroll
            for (int r = 0; r < 4; ++r)
                mb[(size_t)(c0w + mf * 16 + kq * 4 + r) * 256 + nf * 16 + l16] = f2bf(acc[mf][nf][r]);
}

// ---- wbf[b][j][o][i] = bf16( sum_d Mbf[b,o,d] * vwT[j,i,d] ) via MFMA --------
__global__ void __launch_bounds__(512) weff_mfma(const ushort* __restrict__ Mbf,
                                                 const ushort* __restrict__ vwT,
                                                 ushort* __restrict__ wbf) {
    int blk = blockIdx.x;            // 256 blocks, XCD-swizzled; j>=9 idle
    int i = blk >> 3;
    int b = (blk & 7) + 8 * (i >> 4);
    int j = i & 15;
    if (j >= 9) return;
    int tid = threadIdx.x;
    int wid = tid >> 6, lane = tid & 63;
    int wm = wid >> 1, wn = wid & 1;
    int kq = lane >> 4, l16 = lane & 15;
    f32x4 acc[4][8];
#pragma unroll
    for (int mf = 0; mf < 4; ++mf)
#pragma unroll
        for (int nf = 0; nf < 8; ++nf) acc[mf][nf] = (f32x4){0.f, 0.f, 0.f, 0.f};
    const ushort* abase = Mbf + (size_t)b * 65536 + (size_t)(wm * 64 + l16) * 256 + kq * 8;
    const ushort* bbase = vwT + (size_t)(j * 256 + wn * 128 + l16) * 256 + kq * 8;
    for (int kc = 0; kc < 8; ++kc) {
        int d0 = kc * 32;
        short8 af[4], bfr[8];
#pragma unroll
        for (int mf = 0; mf < 4; ++mf) af[mf] = *(const short8*)(abase + mf * 16 * 256 + d0);
#pragma unroll
        for (int nf = 0; nf < 8; ++nf) bfr[nf] = *(const short8*)(bbase + nf * 16 * 256 + d0);
#pragma unroll
        for (int mf = 0; mf < 4; ++mf)
#pragma unroll
            for (int nf = 0; nf < 8; ++nf)
                acc[mf][nf] = __builtin_amdgcn_mfma_f32_16x16x32_bf16(af[mf], bfr[nf], acc[mf][nf], 0, 0, 0);
    }
    ushort* wout = wbf + ((size_t)(b * 9 + j)) * 65536;
#pragma unroll
    for (int mf = 0; mf < 4; ++mf) {
        int o = wm * 64 + mf * 16 + kq * 4;
#pragma unroll
        for (int nf = 0; nf < 8; ++nf) {
            int ic = wn * 128 + nf * 16 + l16;
#pragma unroll
            for (int r = 0; r < 4; ++r)
                wout[(size_t)(o + r) * 256 + ic] = f2bf(acc[mf][nf][r]);
        }
    }
}

// ---- big conv via MFMA, LDS-staged B, XCD-swizzled blocks, residual fused ----
__global__ void __launch_bounds__(512, 4) bigconv_mfma(const ushort* __restrict__ et,
                                                       const ushort* __restrict__ wbf,
                                                       const float* __restrict__ e,
                                                       float* __restrict__ out) {
    int blk = blockIdx.x;            // 512 blocks: XCD-bijective, 2 bs per XCD
    int i = blk >> 3;
    int b = (blk & 7) + 8 * (i >> 5);
    int pt = i & 31;                 // 2 output rows per tile
    int y0 = pt * 2;
    int tid = threadIdx.x, wid = tid >> 6, lane = tid & 63;
    int wm = wid >> 1, wn = wid & 1;
    int kq = lane >> 4, l16 = lane & 15;
    __shared__ ushort Bs[4][64][128];    // 64KB: rows y0-1..y0+2, 128-ch chunk, swizzled
    f32x4 acc[4][4];
#pragma unroll
    for (int mf = 0; mf < 4; ++mf)
#pragma unroll
        for (int nf = 0; nf < 4; ++nf) acc[mf][nf] = (f32x4){0.f, 0.f, 0.f, 0.f};
    const ushort* etb = et + (size_t)b * 1048576;
    const ushort* wb  = wbf + (size_t)b * 589824;
    const short8 zfrag = {};
    // staging role: wave -> row sr (0..3), px-half sph
    int sr = wid >> 1, sph = wid & 1;
    int syc = min(max(y0 - 1 + sr, 0), 63);
    const ushort* srow = etb + (size_t)syc * 64 * 256;
    for (int ci = 0; ci < 2; ++ci) {
        int c0 = ci * 128;
        __syncthreads();
        {
            short8 stg[8];
#pragma unroll
            for (int it = 0; it < 8; ++it) {
                int px = sph * 32 + it * 4 + kq;
                int ug = l16 ^ (px & 15);
                stg[it] = *(const short8*)(srow + (size_t)px * 256 + c0 + ug * 8);
            }
#pragma unroll
            for (int it = 0; it < 8; ++it) {
                int px = sph * 32 + it * 4 + kq;
                *(short8*)(&Bs[sr][px][l16 * 8]) = stg[it];
            }
        }
        __syncthreads();
        for (int tap = 0; tap < 9; ++tap) {
            int dy = tap / 3 - 1, dx = tap % 3 - 1;
            int yy = y0 + wn + dy;
            int rl = wn + dy + 1;
            bool rowok = (yy >= 0 && yy < 64);
#pragma unroll
            for (int kc = 0; kc < 4; ++kc) {
                const ushort* abase = wb + (size_t)tap * 65536 +
                                      (size_t)(wm * 64 + l16) * 256 + c0 + kc * 32 + kq * 8;
                short8 af[4];
#pragma unroll
                for (int mf = 0; mf < 4; ++mf) af[mf] = *(const short8*)(abase + mf * 16 * 256);
                short8 bfr[4];
#pragma unroll
                for (int nf = 0; nf < 4; ++nf) {
                    int pxr = nf * 16 + l16 + dx;
                    bool ok = rowok && (pxr >= 0) && (pxr < 64);
                    int pxc = min(max(pxr, 0), 63);
                    int ul = (kc * 4 + kq) ^ (pxc & 15);
                    short8 v = *(const short8*)(&Bs[rl][pxc][ul * 8]);
                    bfr[nf] = ok ? v : zfrag;
                }
#pragma unroll
                for (int mf = 0; mf < 4; ++mf)
#pragma unroll
                    for (int nf = 0; nf < 4; ++nf)
                        acc[mf][nf] = __builtin_amdgcn_mfma_f32_16x16x32_bf16(af[mf], bfr[nf], acc[mf][nf], 0, 0, 0);
            }
        }
    }
    // epilogue: + residual
    int pcol0 = pt * 128 + wn * 64 + l16;
    const float* eb = e + (size_t)b * NC * NPIX;
    float* ob = out + (size_t)b * NC * NPIX;
#pragma unroll
    for (int mf = 0; mf < 4; ++mf) {
        int o = wm * 64 + mf * 16 + kq * 4;
#pragma unroll
        for (int nf = 0; nf < 4; ++nf) {
            int p = pcol0 + nf * 16;
#pragma unroll
            for (int r = 0; r < 4; ++r) {
                size_t idx = (size_t)(o + r) * NPIX + p;
                ob[idx] = acc[mf][nf][r] + eb[idx];
            }
        }
    }
}

extern "C" void kernel_launch(void* const* d_in, const int* in_sizes, int n_in,
                              void* d_out, int out_size, void* d_ws, size_t ws_size,
                              hipStream_t stream) {
    const float* e   = (const float*)d_in[0];
    const float* pam = (const float*)d_in[1];
    const float* qw  = (const float*)d_in[2];
    const float* kw  = (const float*)d_in[3];
    const float* vw  = (const float*)d_in[4];
    const float* pw  = (const float*)d_in[5];
    float* out = (float*)d_out;
    float* ws  = (float*)d_ws;

    // layout (f32-slot offsets), total ~60.3 MB:
    ushort* et   = (ushort*)ws;                      // 16.78M ushort (33.5MB)
    ushort* wbf  = (ushort*)(ws + 8388608);          // 9.44M ushort (18.9MB)
    float*  S    = ws + 13107200;
    ushort* maxeT = (ushort*)S;                      // 1M ushort
    ushort* pamT  = (ushort*)(S + 524288);           // 1M ushort
    ushort* wqT   = (ushort*)(S + 1048576);          // 589824 ushort
    ushort* wkT   = (ushort*)(S + 1343488);          // 589824 ushort
    ushort* pbf   = (ushort*)(S + 1638400);          // 65536 ushort
    ushort* vwT   = (ushort*)(S + 1671168);          // 589824 ushort
    // reuse: qb/kTb live inside wbf region (dead before weff writes it)
    ushort* qb    = (ushort*)(ws + 8388608);         // 1M ushort
    ushort* kTb   = (ushort*)(ws + 8912896);         // 1M ushort
    ushort* attnT = maxeT;                           // reuse (dead after conv16)
    ushort* Mbf   = pamT;                            // reuse (dead after conv16)

    prep_k<<<2128, 256, 0, stream>>>(e, pam, qw, kw, vw, pw,
                                     maxeT, pamT, wqT, wkT, pbf, vwT, et);
    conv16_mfma<<<128, 512, 0, stream>>>(maxeT, pamT, wqT, wkT, qb, kTb);
    attn_mfma<<<16, 512, 0, stream>>>(qb, kTb, attnT);
    mproj_mfma<<<16, 512, 0, stream>>>(pbf, attnT, Mbf);
    weff_mfma<<<256, 512, 0, stream>>>(Mbf, vwT, wbf);
    bigconv_mfma<<<512, 512, 0, stream>>>(et, wbf, e, out);
}

// Round 5
// 397.880 us; speedup vs baseline: 5.9194x; 1.1384x over previous
//
#include <hip/hip_runtime.h>
#include <hip/hip_bf16.h>

#define NB 16
#define NC 256
#define NPIX 4096

typedef __attribute__((ext_vector_type(8))) short short8;
typedef __attribute__((ext_vector_type(4))) short short4v;
typedef __attribute__((ext_vector_type(4))) float f32x4;

static __device__ __forceinline__ ushort f2bf(float f) {
    __hip_bfloat16 h = __float2bfloat16(f);
    return *(ushort*)&h;
}

// ================= prep: input-only transforms (no nhwc anymore) ==============
// blocks: [0,256) pooltr | [256,512) pamtr | [512,1024) wtap q/k |
//         [1024,1040) projcast | [1040,1104) vw transpose
__global__ void __launch_bounds__(256) prep_k(
    const float* __restrict__ e, const float* __restrict__ pam,
    const float* __restrict__ qw, const float* __restrict__ kw,
    const float* __restrict__ vw, const float* __restrict__ pw,
    ushort* __restrict__ maxeT, ushort* __restrict__ pamT,
    ushort* __restrict__ wqT, ushort* __restrict__ wkT,
    ushort* __restrict__ pbf, ushort* __restrict__ vwT) {
    __shared__ float smem[9216];   // 36 KB max across branches
    int blk = blockIdx.x, t = threadIdx.x;
    if (blk < 512) {
        int isPam = blk >> 8;
        int bb = blk & 255;
        int b = bb >> 4, cg = bb & 15;
        float (*lt)[256] = (float(*)[256])smem;
        if (!isPam) {
            int py = t >> 4, px = t & 15;
#pragma unroll
            for (int cc = 0; cc < 16; ++cc) {
                int c = cg * 16 + cc;
                const float* p = e + (size_t)(b * 256 + c) * NPIX;
                float s = 0.f;
#pragma unroll
                for (int r = 0; r < 4; ++r) {
                    float4 v = *(const float4*)(p + (py * 4 + r) * 64 + px * 4);
                    s += v.x + v.y + v.z + v.w;
                }
                lt[cc][t] = s * 0.0625f;
            }
        } else {
#pragma unroll
            for (int cc = 0; cc < 16; ++cc)
                lt[cc][t] = pam[(size_t)(b * 256 + cg * 16 + cc) * 256 + t];
        }
        __syncthreads();
        ushort* dstb = (isPam ? pamT : maxeT) + (size_t)b * 65536 + (size_t)t * 256 + cg * 16;
#pragma unroll
        for (int g = 0; g < 2; ++g) {
            short8 v;
#pragma unroll
            for (int k = 0; k < 8; ++k) v[k] = (short)f2bf(lt[g * 8 + k][t]);
            *(short8*)(dstb + g * 8) = v;
        }
    } else if (blk < 1024) {
        int idx = blk - 512;
        const float* src = (idx < 256) ? qw : kw;
        ushort* dst = (idx < 256) ? wqT : wkT;
        int o = idx & 255;
        float wv[9];
#pragma unroll
        for (int j = 0; j < 9; ++j) wv[j] = src[(size_t)o * 2304 + t * 9 + j];
#pragma unroll
        for (int j = 0; j < 9; ++j) dst[(size_t)j * 65536 + (size_t)o * 256 + t] = f2bf(wv[j]);
    } else if (blk < 1040) {
        int base = (blk - 1024) * 4096;
        for (int g = 0; g < 16; ++g) {
            int idx = base + g * 256 + t;
            pbf[idx] = f2bf(pw[idx]);
        }
    } else {
        // vw transpose: vwT[j][i][d] = bf16(vw[d][i*9+j]), d-chunk of 4
        int d0 = (blk - 1040) * 4;
        float* lt = smem;   // flat [4][2304]
        for (int u = 0; u < 36; ++u) lt[u * 256 + t] = vw[(size_t)d0 * 2304 + u * 256 + t];
        __syncthreads();
#pragma unroll
        for (int r = 0; r < 9; ++r) {
            int idx = r * 256 + t;
            int i = idx / 9, j = idx % 9;
            short4v v;
#pragma unroll
            for (int dd = 0; dd < 4; ++dd) v[dd] = (short)f2bf(lt[dd * 2304 + idx]);
            *(short4v*)(vwT + ((size_t)(j * 256 + i)) * 256 + d0) = v;
        }
    }
}

// ---- conv16 via MFMA + L2 norm; q (blk<64) and k halves in one launch --------
__global__ void __launch_bounds__(512) conv16_mfma(const ushort* __restrict__ maxeT,
                                                   const ushort* __restrict__ pamT,
                                                   const ushort* __restrict__ wqT,
                                                   const ushort* __restrict__ wkT,
                                                   ushort* __restrict__ qb,
                                                   ushort* __restrict__ kTb) {
    int blk = blockIdx.x;
    const ushort* inT = (blk < 64) ? maxeT : pamT;
    const ushort* wt  = (blk < 64) ? wqT : wkT;
    ushort* outp      = (blk < 64) ? qb : kTb;
    int bb = blk & 63;
    int b = bb >> 2, o0 = (bb & 3) * 64;
    int tid = threadIdx.x;
    int wid = tid >> 6, lane = tid & 63;
    int wm = wid >> 1, wn = wid & 1;
    int kq = lane >> 4, l16 = lane & 15;
    f32x4 acc[8];
#pragma unroll
    for (int nf = 0; nf < 8; ++nf) acc[nf] = (f32x4){0.f, 0.f, 0.f, 0.f};
    const ushort* itb = inT + (size_t)b * 65536;
    const short8 zfrag = {};
    for (int tap = 0; tap < 9; ++tap) {
        int dy = tap / 3 - 1, dx = tap % 3 - 1;
        const ushort* bbase[8]; bool bval[8];
#pragma unroll
        for (int nf = 0; nf < 8; ++nf) {
            int n = wn * 128 + nf * 16 + l16;
            int yy = (n >> 4) + dy, xx = (n & 15) + dx;
            bval[nf] = (yy >= 0 && yy < 16 && xx >= 0 && xx < 16);
            int nn = ((yy & 15) << 4) | (xx & 15);
            bbase[nf] = itb + (size_t)nn * 256 + kq * 8;
        }
        const ushort* abase = wt + (size_t)tap * 65536 + (size_t)(o0 + wm * 16 + l16) * 256 + kq * 8;
        for (int kc = 0; kc < 8; ++kc) {
            short8 af = *(const short8*)(abase + kc * 32);
#pragma unroll
            for (int nf = 0; nf < 8; ++nf) {
                short8 bf = bval[nf] ? *(const short8*)(bbase[nf] + kc * 32) : zfrag;
                acc[nf] = __builtin_amdgcn_mfma_f32_16x16x32_bf16(af, bf, acc[nf], 0, 0, 0);
            }
        }
    }
    __shared__ float nrm[64][2];
    float ss[4] = {0.f, 0.f, 0.f, 0.f};
#pragma unroll
    for (int nf = 0; nf < 8; ++nf)
#pragma unroll
        for (int r = 0; r < 4; ++r) ss[r] += acc[nf][r] * acc[nf][r];
#pragma unroll
    for (int r = 0; r < 4; ++r) {
#pragma unroll
        for (int off = 1; off < 16; off <<= 1) ss[r] += __shfl_xor(ss[r], off, 64);
    }
    if (l16 == 0) {
#pragma unroll
        for (int r = 0; r < 4; ++r) nrm[wm * 16 + kq * 4 + r][wn] = ss[r];
    }
    __syncthreads();
    float rn[4];
#pragma unroll
    for (int r = 0; r < 4; ++r) {
        int row = wm * 16 + kq * 4 + r;
        float tot = nrm[row][0] + nrm[row][1];
        rn[r] = 1.0f / fmaxf(sqrtf(tot), 1e-12f);
    }
    ushort* ob = outp + (size_t)b * 65536;
#pragma unroll
    for (int nf = 0; nf < 8; ++nf) {
        int col = wn * 128 + nf * 16 + l16;
#pragma unroll
        for (int r = 0; r < 4; ++r) {
            int row = o0 + wm * 16 + kq * 4 + r;
            ob[(size_t)row * 256 + col] = f2bf(acc[nf][r] * rn[r]);
        }
    }
}

// ---- attn via MFMA + softmax; 64 blocks (b x 4 row-groups); attnT[d][c] ------
__global__ void __launch_bounds__(512) attn_mfma(const ushort* __restrict__ qb,
                                                 const ushort* __restrict__ kTb,
                                                 ushort* __restrict__ attnT) {
    int blk = blockIdx.x;
    int b = (blk & 7) + 8 * ((blk >> 3) & 1);
    int cg = blk >> 4;
    int tid = threadIdx.x, wid = tid >> 6, lane = tid & 63;
    int rw = wid & 3, chf = wid >> 2;
    int kq = lane >> 4, l16 = lane & 15;
    int c0w = cg * 64 + rw * 16;
    int lrow = rw * 16 + kq * 4;
    f32x4 acc[8];
#pragma unroll
    for (int nf = 0; nf < 8; ++nf) acc[nf] = (f32x4){0.f, 0.f, 0.f, 0.f};
    const ushort* qp = qb + (size_t)b * 65536;
    const ushort* kp = kTb + (size_t)b * 65536 + (size_t)(chf * 128) * 256;
    for (int kc = 0; kc < 8; ++kc) {
        short8 af = *(const short8*)(qp + (size_t)(c0w + l16) * 256 + kc * 32 + kq * 8);
#pragma unroll
        for (int nf = 0; nf < 8; ++nf) {
            short8 bf = *(const short8*)(kp + (size_t)(nf * 16 + l16) * 256 + kc * 32 + kq * 8);
            acc[nf] = __builtin_amdgcn_mfma_f32_16x16x32_bf16(af, bf, acc[nf], 0, 0, 0);
        }
    }
    __shared__ float red[64][2];
    float m4[4], s4[4];
#pragma unroll
    for (int r = 0; r < 4; ++r) {
        float m = -1e30f;
#pragma unroll
        for (int nf = 0; nf < 8; ++nf) m = fmaxf(m, acc[nf][r] * 0.0625f);
#pragma unroll
        for (int off = 1; off < 16; off <<= 1) m = fmaxf(m, __shfl_xor(m, off, 64));
        m4[r] = m;
    }
    if (l16 == 0) {
#pragma unroll
        for (int r = 0; r < 4; ++r) red[lrow + r][chf] = m4[r];
    }
    __syncthreads();
#pragma unroll
    for (int r = 0; r < 4; ++r) m4[r] = fmaxf(red[lrow + r][0], red[lrow + r][1]);
    __syncthreads();
#pragma unroll
    for (int r = 0; r < 4; ++r) {
        float s = 0.f;
#pragma unroll
        for (int nf = 0; nf < 8; ++nf) {
            float ex = __expf(acc[nf][r] * 0.0625f - m4[r]);
            acc[nf][r] = ex;
            s += ex;
        }
#pragma unroll
        for (int off = 1; off < 16; off <<= 1) s += __shfl_xor(s, off, 64);
        s4[r] = s;
    }
    if (l16 == 0) {
#pragma unroll
        for (int r = 0; r < 4; ++r) red[lrow + r][chf] = s4[r];
    }
    __syncthreads();
#pragma unroll
    for (int r = 0; r < 4; ++r) {
        float inv = 1.0f / (red[lrow + r][0] + red[lrow + r][1]);
#pragma unroll
        for (int nf = 0; nf < 8; ++nf) acc[nf][r] *= inv;
    }
    ushort* ap = attnT + (size_t)b * 65536;
#pragma unroll
    for (int nf = 0; nf < 8; ++nf) {
        int d = chf * 128 + nf * 16 + l16;
        short4v v;
#pragma unroll
        for (int r = 0; r < 4; ++r) v[r] = (short)f2bf(acc[nf][r]);
        *(short4v*)(ap + (size_t)d * 256 + c0w + kq * 4) = v;
    }
}

// ---- Mbf[b][o][d] = bf16( sum_c pbf[o,c] * attnT[d,c] ); 64 blocks -----------
__global__ void __launch_bounds__(512) mproj_mfma(const ushort* __restrict__ pbf,
                                                  const ushort* __restrict__ attnT,
                                                  ushort* __restrict__ Mbf) {
    int blk = blockIdx.x;
    int b = (blk & 7) + 8 * ((blk >> 3) & 1);
    int og = blk >> 4;
    int tid = threadIdx.x, wid = tid >> 6, lane = tid & 63;
    int rw = wid & 3, chf = wid >> 2;
    int kq = lane >> 4, l16 = lane & 15;
    int o0w = og * 64 + rw * 16;
    f32x4 acc[8];
#pragma unroll
    for (int nf = 0; nf < 8; ++nf) acc[nf] = (f32x4){0.f, 0.f, 0.f, 0.f};
    const ushort* ap = attnT + (size_t)b * 65536 + (size_t)(chf * 128) * 256;
    for (int kc = 0; kc < 8; ++kc) {
        short8 af = *(const short8*)(pbf + (size_t)(o0w + l16) * 256 + kc * 32 + kq * 8);
#pragma unroll
        for (int nf = 0; nf < 8; ++nf) {
            short8 bf = *(const short8*)(ap + (size_t)(nf * 16 + l16) * 256 + kc * 32 + kq * 8);
            acc[nf] = __builtin_amdgcn_mfma_f32_16x16x32_bf16(af, bf, acc[nf], 0, 0, 0);
        }
    }
    ushort* mb = Mbf + (size_t)b * 65536;
#pragma unroll
    for (int nf = 0; nf < 8; ++nf)
#pragma unroll
        for (int r = 0; r < 4; ++r)
            mb[(size_t)(o0w + kq * 4 + r) * 256 + chf * 128 + nf * 16 + l16] = f2bf(acc[nf][r]);
}

// ---- wbf[b][j][o][i] = bf16( sum_d Mbf[b,o,d] * vwT[j,i,d] ) via MFMA --------
__global__ void __launch_bounds__(512) weff_mfma(const ushort* __restrict__ Mbf,
                                                 const ushort* __restrict__ vwT,
                                                 ushort* __restrict__ wbf) {
    int blk = blockIdx.x;            // 256 blocks, XCD-swizzled; j>=9 idle
    int i = blk >> 3;
    int b = (blk & 7) + 8 * (i >> 4);
    int j = i & 15;
    if (j >= 9) return;
    int tid = threadIdx.x;
    int wid = tid >> 6, lane = tid & 63;
    int wm = wid >> 1, wn = wid & 1;
    int kq = lane >> 4, l16 = lane & 15;
    f32x4 acc[4][8];
#pragma unroll
    for (int mf = 0; mf < 4; ++mf)
#pragma unroll
        for (int nf = 0; nf < 8; ++nf) acc[mf][nf] = (f32x4){0.f, 0.f, 0.f, 0.f};
    const ushort* abase = Mbf + (size_t)b * 65536 + (size_t)(wm * 64 + l16) * 256 + kq * 8;
    const ushort* bbase = vwT + (size_t)(j * 256 + wn * 128 + l16) * 256 + kq * 8;
    for (int kc = 0; kc < 8; ++kc) {
        int d0 = kc * 32;
        short8 af[4], bfr[8];
#pragma unroll
        for (int mf = 0; mf < 4; ++mf) af[mf] = *(const short8*)(abase + mf * 16 * 256 + d0);
#pragma unroll
        for (int nf = 0; nf < 8; ++nf) bfr[nf] = *(const short8*)(bbase + nf * 16 * 256 + d0);
#pragma unroll
        for (int mf = 0; mf < 4; ++mf)
#pragma unroll
            for (int nf = 0; nf < 8; ++nf)
                acc[mf][nf] = __builtin_amdgcn_mfma_f32_16x16x32_bf16(af[mf], bfr[nf], acc[mf][nf], 0, 0, 0);
    }
    ushort* wout = wbf + ((size_t)(b * 9 + j)) * 65536;
#pragma unroll
    for (int mf = 0; mf < 4; ++mf) {
        int o = wm * 64 + mf * 16 + kq * 4;
#pragma unroll
        for (int nf = 0; nf < 8; ++nf) {
            int ic = wn * 128 + nf * 16 + l16;
#pragma unroll
            for (int r = 0; r < 4; ++r)
                wout[(size_t)(o + r) * 256 + ic] = f2bf(acc[mf][nf][r]);
        }
    }
}

// ---- big conv: fused NHWC staging from e + reg-A per tap + MFMA + residual ---
__global__ void __launch_bounds__(512, 2) bigconv_mfma(const float* __restrict__ e,
                                                       const ushort* __restrict__ wbf,
                                                       float* __restrict__ out) {
    int blk = blockIdx.x;            // 512 blocks: XCD-bijective
    int ib = blk >> 3;
    int b = (blk & 7) + 8 * (ib >> 5);
    int pt = ib & 31;                // 2 output rows per tile
    int y0 = pt * 2;
    int tid = threadIdx.x, wid = tid >> 6, lane = tid & 63;
    int wm = wid >> 1, wn = wid & 1;
    int kq = lane >> 4, l16 = lane & 15;
    __shared__ ushort Bs[4][64][128];    // 64KB, XOR-swizzled ch-units
    f32x4 acc[4][4];
#pragma unroll
    for (int mf = 0; mf < 4; ++mf)
#pragma unroll
        for (int nf = 0; nf < 4; ++nf) acc[mf][nf] = (f32x4){0.f, 0.f, 0.f, 0.f};
    const float* eb = e + (size_t)b * NC * NPIX;
    const ushort* wb = wbf + (size_t)b * 589824;
    const short8 zf = {};
    // staging roles: c2 = channel-pair (0..63), sr = row (0..3), sh = px half
    int c2 = tid & 63, rp = tid >> 6;
    int sr = rp >> 1, sh = rp & 1;
    int syc = min(max(y0 - 1 + sr, 0), 63);

    auto loada = [&](short8 (&af)[4][4], const ushort* abw, int tap) {
        const ushort* ab = abw + (size_t)tap * 65536;
#pragma unroll
        for (int mf = 0; mf < 4; ++mf)
#pragma unroll
            for (int kc = 0; kc < 4; ++kc)
                af[mf][kc] = *(const short8*)(ab + mf * 4096 + kc * 32);
    };
    auto compute = [&](short8 (&af)[4][4], int tap) {
        int dy = tap / 3 - 1, dx = tap % 3 - 1;
        int rl = wn + dy + 1;
        bool rowok = (unsigned)(y0 + wn + dy) < 64u;
        const ushort* bp[4]; bool ok[4]; int px15[4];
#pragma unroll
        for (int nf = 0; nf < 4; ++nf) {
            int pxr = nf * 16 + l16 + dx;
            ok[nf] = rowok && ((unsigned)pxr < 64u);
            int pxc = min(max(pxr, 0), 63);
            bp[nf] = &Bs[rl][pxc][0];
            px15[nf] = pxc & 15;
        }
#pragma unroll
        for (int kc = 0; kc < 4; ++kc) {
            short8 bfr[4];
#pragma unroll
            for (int nf = 0; nf < 4; ++nf) {
                short8 v = *(const short8*)(bp[nf] + (((kc * 4 + kq) ^ px15[nf]) * 8));
                bfr[nf] = ok[nf] ? v : zf;
            }
#pragma unroll
            for (int mf = 0; mf < 4; ++mf)
#pragma unroll
                for (int nf = 0; nf < 4; ++nf)
                    acc[mf][nf] = __builtin_amdgcn_mfma_f32_16x16x32_bf16(af[mf][kc], bfr[nf], acc[mf][nf], 0, 0, 0);
        }
    };

    for (int ci = 0; ci < 2; ++ci) {
        int c0 = ci * 128;
        __syncthreads();
        // ---- stage: e NCHW f32 -> Bs bf16 swizzled (fused NHWC transform) ----
        {
            const float* s0 = eb + ((size_t)(c0 + 2 * c2) * 64 + syc) * 64 + sh * 32;
            const float* s1 = s0 + NPIX;
            float4 va[8], vb[8];
#pragma unroll
            for (int q = 0; q < 8; ++q) va[q] = *(const float4*)(s0 + q * 4);
#pragma unroll
            for (int q = 0; q < 8; ++q) vb[q] = *(const float4*)(s1 + q * 4);
            uint* bsrow = (uint*)&Bs[sr][0][0];
#pragma unroll
            for (int q = 0; q < 8; ++q) {
#pragma unroll
                for (int m2 = 0; m2 < 4; ++m2) {
                    int px = sh * 32 + q * 4 + m2;
                    float f0 = ((const float*)&va[q])[m2];
                    float f1 = ((const float*)&vb[q])[m2];
                    uint pk = (uint)f2bf(f0) | ((uint)f2bf(f1) << 16);
                    int us = (c2 >> 2) ^ (px & 15);
                    bsrow[px * 64 + us * 4 + (c2 & 3)] = pk;
                }
            }
        }
        __syncthreads();
        // ---- compute: 9 taps, A in regs with one-tap prefetch ----
        const ushort* abw = wb + (size_t)(wm * 64 + l16) * 256 + c0 + kq * 8;
        short8 a0[4][4], a1[4][4];
        loada(a0, abw, 0);
#pragma unroll
        for (int tt = 0; tt < 4; ++tt) {
            loada(a1, abw, tt * 2 + 1);
            compute(a0, tt * 2);
            loada(a0, abw, tt * 2 + 2);
            compute(a1, tt * 2 + 1);
        }
        compute(a0, 8);
    }
    // ---- epilogue: + residual ----
    int pcol0 = pt * 128 + wn * 64 + l16;
    float* ob = out + (size_t)b * NC * NPIX;
#pragma unroll
    for (int mf = 0; mf < 4; ++mf) {
        int o = wm * 64 + mf * 16 + kq * 4;
#pragma unroll
        for (int nf = 0; nf < 4; ++nf) {
            int p = pcol0 + nf * 16;
#pragma unroll
            for (int r = 0; r < 4; ++r) {
                size_t idx = (size_t)(o + r) * NPIX + p;
                ob[idx] = acc[mf][nf][r] + eb[idx];
            }
        }
    }
}

extern "C" void kernel_launch(void* const* d_in, const int* in_sizes, int n_in,
                              void* d_out, int out_size, void* d_ws, size_t ws_size,
                              hipStream_t stream) {
    const float* e   = (const float*)d_in[0];
    const float* pam = (const float*)d_in[1];
    const float* qw  = (const float*)d_in[2];
    const float* kw  = (const float*)d_in[3];
    const float* vw  = (const float*)d_in[4];
    const float* pw  = (const float*)d_in[5];
    float* out = (float*)d_out;
    float* ws  = (float*)d_ws;

    // layout (f32-slot offsets), total ~26.7 MB:
    ushort* wbf  = (ushort*)ws;                      // 9,437,184 ushorts (18.9MB)
    float*  S    = ws + 4718592;
    ushort* maxeT = (ushort*)S;                      // 1,048,576 ushorts
    ushort* pamT  = (ushort*)(S + 524288);           // 1,048,576 ushorts
    ushort* wqT   = (ushort*)(S + 1048576);          // 589,824 ushorts
    ushort* wkT   = (ushort*)(S + 1343488);          // 589,824 ushorts
    ushort* pbf   = (ushort*)(S + 1638400);          // 65,536 ushorts
    ushort* vwT   = (ushort*)(S + 1671168);          // 589,824 ushorts
    // reuse: qb/kTb inside wbf region (dead before weff writes it)
    ushort* qb    = (ushort*)ws;                     // 1,048,576 ushorts
    ushort* kTb   = (ushort*)(ws + 524288);          // 1,048,576 ushorts
    ushort* attnT = maxeT;                           // reuse (dead after conv16)
    ushort* Mbf   = pamT;                            // reuse (dead after conv16)

    prep_k<<<1104, 256, 0, stream>>>(e, pam, qw, kw, vw, pw,
                                     maxeT, pamT, wqT, wkT, pbf, vwT);
    conv16_mfma<<<128, 512, 0, stream>>>(maxeT, pamT, wqT, wkT, qb, kTb);
    attn_mfma<<<64, 512, 0, stream>>>(qb, kTb, attnT);
    mproj_mfma<<<64, 512, 0, stream>>>(pbf, attnT, Mbf);
    weff_mfma<<<256, 512, 0, stream>>>(Mbf, vwT, wbf);
    bigconv_mfma<<<512, 512, 0, stream>>>(e, wbf, out);
}

// Round 6
// 325.719 us; speedup vs baseline: 7.2308x; 1.2215x over previous
//
#include <hip/hip_runtime.h>
#include <hip/hip_bf16.h>

#define NB 16
#define NC 256
#define NPIX 4096

typedef __attribute__((ext_vector_type(8))) short short8;
typedef __attribute__((ext_vector_type(4))) short short4v;
typedef __attribute__((ext_vector_type(4))) float f32x4;

static __device__ __forceinline__ ushort f2bf(float f) {
    __hip_bfloat16 h = __float2bfloat16(f);
    return *(ushort*)&h;
}

static __device__ __forceinline__ void gload_lds16(const ushort* g, ushort* l) {
    __builtin_amdgcn_global_load_lds(
        (const __attribute__((address_space(1))) unsigned int*)g,
        (__attribute__((address_space(3))) unsigned int*)l, 16, 0, 0);
}

// ================= prep: input-only transforms ================================
// blocks: [0,256) pooltr | [256,512) pamtr | [512,1024) wtap q/k |
//         [1024,1040) projcast | [1040,1104) vw transpose
__global__ void __launch_bounds__(256) prep_k(
    const float* __restrict__ e, const float* __restrict__ pam,
    const float* __restrict__ qw, const float* __restrict__ kw,
    const float* __restrict__ vw, const float* __restrict__ pw,
    ushort* __restrict__ maxeT, ushort* __restrict__ pamT,
    ushort* __restrict__ wqT, ushort* __restrict__ wkT,
    ushort* __restrict__ pbf, ushort* __restrict__ vwT) {
    __shared__ float smem[9216];   // 36 KB max across branches
    int blk = blockIdx.x, t = threadIdx.x;
    if (blk < 512) {
        int isPam = blk >> 8;
        int bb = blk & 255;
        int b = bb >> 4, cg = bb & 15;
        float (*lt)[256] = (float(*)[256])smem;
        if (!isPam) {
            int py = t >> 4, px = t & 15;
#pragma unroll
            for (int cc = 0; cc < 16; ++cc) {
                int c = cg * 16 + cc;
                const float* p = e + (size_t)(b * 256 + c) * NPIX;
                float s = 0.f;
#pragma unroll
                for (int r = 0; r < 4; ++r) {
                    float4 v = *(const float4*)(p + (py * 4 + r) * 64 + px * 4);
                    s += v.x + v.y + v.z + v.w;
                }
                lt[cc][t] = s * 0.0625f;
            }
        } else {
#pragma unroll
            for (int cc = 0; cc < 16; ++cc)
                lt[cc][t] = pam[(size_t)(b * 256 + cg * 16 + cc) * 256 + t];
        }
        __syncthreads();
        ushort* dstb = (isPam ? pamT : maxeT) + (size_t)b * 65536 + (size_t)t * 256 + cg * 16;
#pragma unroll
        for (int g = 0; g < 2; ++g) {
            short8 v;
#pragma unroll
            for (int k = 0; k < 8; ++k) v[k] = (short)f2bf(lt[g * 8 + k][t]);
            *(short8*)(dstb + g * 8) = v;
        }
    } else if (blk < 1024) {
        int idx = blk - 512;
        const float* src = (idx < 256) ? qw : kw;
        ushort* dst = (idx < 256) ? wqT : wkT;
        int o = idx & 255;
        float wv[9];
#pragma unroll
        for (int j = 0; j < 9; ++j) wv[j] = src[(size_t)o * 2304 + t * 9 + j];
#pragma unroll
        for (int j = 0; j < 9; ++j) dst[(size_t)j * 65536 + (size_t)o * 256 + t] = f2bf(wv[j]);
    } else if (blk < 1040) {
        int base = (blk - 1024) * 4096;
        for (int g = 0; g < 16; ++g) {
            int idx = base + g * 256 + t;
            pbf[idx] = f2bf(pw[idx]);
        }
    } else {
        int d0 = (blk - 1040) * 4;
        float* lt = smem;   // flat [4][2304]
        for (int u = 0; u < 36; ++u) lt[u * 256 + t] = vw[(size_t)d0 * 2304 + u * 256 + t];
        __syncthreads();
#pragma unroll
        for (int r = 0; r < 9; ++r) {
            int idx = r * 256 + t;
            int i = idx / 9, j = idx % 9;
            short4v v;
#pragma unroll
            for (int dd = 0; dd < 4; ++dd) v[dd] = (short)f2bf(lt[dd * 2304 + idx]);
            *(short4v*)(vwT + ((size_t)(j * 256 + i)) * 256 + d0) = v;
        }
    }
}

// ---- conv16 via MFMA + L2 norm; q (blk<64) and k halves in one launch --------
__global__ void __launch_bounds__(512) conv16_mfma(const ushort* __restrict__ maxeT,
                                                   const ushort* __restrict__ pamT,
                                                   const ushort* __restrict__ wqT,
                                                   const ushort* __restrict__ wkT,
                                                   ushort* __restrict__ qb,
                                                   ushort* __restrict__ kTb) {
    int blk = blockIdx.x;
    const ushort* inT = (blk < 64) ? maxeT : pamT;
    const ushort* wt  = (blk < 64) ? wqT : wkT;
    ushort* outp      = (blk < 64) ? qb : kTb;
    int bb = blk & 63;
    int b = bb >> 2, o0 = (bb & 3) * 64;
    int tid = threadIdx.x;
    int wid = tid >> 6, lane = tid & 63;
    int wm = wid >> 1, wn = wid & 1;
    int kq = lane >> 4, l16 = lane & 15;
    f32x4 acc[8];
#pragma unroll
    for (int nf = 0; nf < 8; ++nf) acc[nf] = (f32x4){0.f, 0.f, 0.f, 0.f};
    const ushort* itb = inT + (size_t)b * 65536;
    const short8 zfrag = {};
    for (int tap = 0; tap < 9; ++tap) {
        int dy = tap / 3 - 1, dx = tap % 3 - 1;
        const ushort* bbase[8]; bool bval[8];
#pragma unroll
        for (int nf = 0; nf < 8; ++nf) {
            int n = wn * 128 + nf * 16 + l16;
            int yy = (n >> 4) + dy, xx = (n & 15) + dx;
            bval[nf] = (yy >= 0 && yy < 16 && xx >= 0 && xx < 16);
            int nn = ((yy & 15) << 4) | (xx & 15);
            bbase[nf] = itb + (size_t)nn * 256 + kq * 8;
        }
        const ushort* abase = wt + (size_t)tap * 65536 + (size_t)(o0 + wm * 16 + l16) * 256 + kq * 8;
        for (int kc = 0; kc < 8; ++kc) {
            short8 af = *(const short8*)(abase + kc * 32);
#pragma unroll
            for (int nf = 0; nf < 8; ++nf) {
                short8 bf = bval[nf] ? *(const short8*)(bbase[nf] + kc * 32) : zfrag;
                acc[nf] = __builtin_amdgcn_mfma_f32_16x16x32_bf16(af, bf, acc[nf], 0, 0, 0);
            }
        }
    }
    __shared__ float nrm[64][2];
    float ss[4] = {0.f, 0.f, 0.f, 0.f};
#pragma unroll
    for (int nf = 0; nf < 8; ++nf)
#pragma unroll
        for (int r = 0; r < 4; ++r) ss[r] += acc[nf][r] * acc[nf][r];
#pragma unroll
    for (int r = 0; r < 4; ++r) {
#pragma unroll
        for (int off = 1; off < 16; off <<= 1) ss[r] += __shfl_xor(ss[r], off, 64);
    }
    if (l16 == 0) {
#pragma unroll
        for (int r = 0; r < 4; ++r) nrm[wm * 16 + kq * 4 + r][wn] = ss[r];
    }
    __syncthreads();
    float rn[4];
#pragma unroll
    for (int r = 0; r < 4; ++r) {
        int row = wm * 16 + kq * 4 + r;
        float tot = nrm[row][0] + nrm[row][1];
        rn[r] = 1.0f / fmaxf(sqrtf(tot), 1e-12f);
    }
    ushort* ob = outp + (size_t)b * 65536;
#pragma unroll
    for (int nf = 0; nf < 8; ++nf) {
        int col = wn * 128 + nf * 16 + l16;
#pragma unroll
        for (int r = 0; r < 4; ++r) {
            int row = o0 + wm * 16 + kq * 4 + r;
            ob[(size_t)row * 256 + col] = f2bf(acc[nf][r] * rn[r]);
        }
    }
}

// ---- attn via MFMA + softmax; 64 blocks (b x 4 row-groups); attnT[d][c] ------
__global__ void __launch_bounds__(512) attn_mfma(const ushort* __restrict__ qb,
                                                 const ushort* __restrict__ kTb,
                                                 ushort* __restrict__ attnT) {
    int blk = blockIdx.x;
    int b = (blk & 7) + 8 * ((blk >> 3) & 1);
    int cg = blk >> 4;
    int tid = threadIdx.x, wid = tid >> 6, lane = tid & 63;
    int rw = wid & 3, chf = wid >> 2;
    int kq = lane >> 4, l16 = lane & 15;
    int c0w = cg * 64 + rw * 16;
    int lrow = rw * 16 + kq * 4;
    f32x4 acc[8];
#pragma unroll
    for (int nf = 0; nf < 8; ++nf) acc[nf] = (f32x4){0.f, 0.f, 0.f, 0.f};
    const ushort* qp = qb + (size_t)b * 65536;
    const ushort* kp = kTb + (size_t)b * 65536 + (size_t)(chf * 128) * 256;
    for (int kc = 0; kc < 8; ++kc) {
        short8 af = *(const short8*)(qp + (size_t)(c0w + l16) * 256 + kc * 32 + kq * 8);
#pragma unroll
        for (int nf = 0; nf < 8; ++nf) {
            short8 bf = *(const short8*)(kp + (size_t)(nf * 16 + l16) * 256 + kc * 32 + kq * 8);
            acc[nf] = __builtin_amdgcn_mfma_f32_16x16x32_bf16(af, bf, acc[nf], 0, 0, 0);
        }
    }
    __shared__ float red[64][2];
    float m4[4], s4[4];
#pragma unroll
    for (int r = 0; r < 4; ++r) {
        float m = -1e30f;
#pragma unroll
        for (int nf = 0; nf < 8; ++nf) m = fmaxf(m, acc[nf][r] * 0.0625f);
#pragma unroll
        for (int off = 1; off < 16; off <<= 1) m = fmaxf(m, __shfl_xor(m, off, 64));
        m4[r] = m;
    }
    if (l16 == 0) {
#pragma unroll
        for (int r = 0; r < 4; ++r) red[lrow + r][chf] = m4[r];
    }
    __syncthreads();
#pragma unroll
    for (int r = 0; r < 4; ++r) m4[r] = fmaxf(red[lrow + r][0], red[lrow + r][1]);
    __syncthreads();
#pragma unroll
    for (int r = 0; r < 4; ++r) {
        float s = 0.f;
#pragma unroll
        for (int nf = 0; nf < 8; ++nf) {
            float ex = __expf(acc[nf][r] * 0.0625f - m4[r]);
            acc[nf][r] = ex;
            s += ex;
        }
#pragma unroll
        for (int off = 1; off < 16; off <<= 1) s += __shfl_xor(s, off, 64);
        s4[r] = s;
    }
    if (l16 == 0) {
#pragma unroll
        for (int r = 0; r < 4; ++r) red[lrow + r][chf] = s4[r];
    }
    __syncthreads();
#pragma unroll
    for (int r = 0; r < 4; ++r) {
        float inv = 1.0f / (red[lrow + r][0] + red[lrow + r][1]);
#pragma unroll
        for (int nf = 0; nf < 8; ++nf) acc[nf][r] *= inv;
    }
    ushort* ap = attnT + (size_t)b * 65536;
#pragma unroll
    for (int nf = 0; nf < 8; ++nf) {
        int d = chf * 128 + nf * 16 + l16;
        short4v v;
#pragma unroll
        for (int r = 0; r < 4; ++r) v[r] = (short)f2bf(acc[nf][r]);
        *(short4v*)(ap + (size_t)d * 256 + c0w + kq * 4) = v;
    }
}

// ---- Mbf[b][o][d] = bf16( sum_c pbf[o,c] * attnT[d,c] ); 64 blocks -----------
__global__ void __launch_bounds__(512) mproj_mfma(const ushort* __restrict__ pbf,
                                                  const ushort* __restrict__ attnT,
                                                  ushort* __restrict__ Mbf) {
    int blk = blockIdx.x;
    int b = (blk & 7) + 8 * ((blk >> 3) & 1);
    int og = blk >> 4;
    int tid = threadIdx.x, wid = tid >> 6, lane = tid & 63;
    int rw = wid & 3, chf = wid >> 2;
    int kq = lane >> 4, l16 = lane & 15;
    int o0w = og * 64 + rw * 16;
    f32x4 acc[8];
#pragma unroll
    for (int nf = 0; nf < 8; ++nf) acc[nf] = (f32x4){0.f, 0.f, 0.f, 0.f};
    const ushort* ap = attnT + (size_t)b * 65536 + (size_t)(chf * 128) * 256;
    for (int kc = 0; kc < 8; ++kc) {
        short8 af = *(const short8*)(pbf + (size_t)(o0w + l16) * 256 + kc * 32 + kq * 8);
#pragma unroll
        for (int nf = 0; nf < 8; ++nf) {
            short8 bf = *(const short8*)(ap + (size_t)(nf * 16 + l16) * 256 + kc * 32 + kq * 8);
            acc[nf] = __builtin_amdgcn_mfma_f32_16x16x32_bf16(af, bf, acc[nf], 0, 0, 0);
        }
    }
    ushort* mb = Mbf + (size_t)b * 65536;
#pragma unroll
    for (int nf = 0; nf < 8; ++nf)
#pragma unroll
        for (int r = 0; r < 4; ++r)
            mb[(size_t)(o0w + kq * 4 + r) * 256 + chf * 128 + nf * 16 + l16] = f2bf(acc[nf][r]);
}

// ---- wbf[b][j][o][i] = bf16( sum_d Mbf[b,o,d] * vwT[j,i,d] ) via MFMA --------
__global__ void __launch_bounds__(512) weff_mfma(const ushort* __restrict__ Mbf,
                                                 const ushort* __restrict__ vwT,
                                                 ushort* __restrict__ wbf) {
    int blk = blockIdx.x;            // 256 blocks, XCD-swizzled; j>=9 idle
    int i = blk >> 3;
    int b = (blk & 7) + 8 * (i >> 4);
    int j = i & 15;
    if (j >= 9) return;
    int tid = threadIdx.x;
    int wid = tid >> 6, lane = tid & 63;
    int wm = wid >> 1, wn = wid & 1;
    int kq = lane >> 4, l16 = lane & 15;
    f32x4 acc[4][8];
#pragma unroll
    for (int mf = 0; mf < 4; ++mf)
#pragma unroll
        for (int nf = 0; nf < 8; ++nf) acc[mf][nf] = (f32x4){0.f, 0.f, 0.f, 0.f};
    const ushort* abase = Mbf + (size_t)b * 65536 + (size_t)(wm * 64 + l16) * 256 + kq * 8;
    const ushort* bbase = vwT + (size_t)(j * 256 + wn * 128 + l16) * 256 + kq * 8;
    for (int kc = 0; kc < 8; ++kc) {
        int d0 = kc * 32;
        short8 af[4], bfr[8];
#pragma unroll
        for (int mf = 0; mf < 4; ++mf) af[mf] = *(const short8*)(abase + mf * 16 * 256 + d0);
#pragma unroll
        for (int nf = 0; nf < 8; ++nf) bfr[nf] = *(const short8*)(bbase + nf * 16 * 256 + d0);
#pragma unroll
        for (int mf = 0; mf < 4; ++mf)
#pragma unroll
            for (int nf = 0; nf < 8; ++nf)
                acc[mf][nf] = __builtin_amdgcn_mfma_f32_16x16x32_bf16(af[mf], bfr[nf], acc[mf][nf], 0, 0, 0);
    }
    ushort* wout = wbf + ((size_t)(b * 9 + j)) * 65536;
#pragma unroll
    for (int mf = 0; mf < 4; ++mf) {
        int o = wm * 64 + mf * 16 + kq * 4;
#pragma unroll
        for (int nf = 0; nf < 8; ++nf) {
            int ic = wn * 128 + nf * 16 + l16;
#pragma unroll
            for (int r = 0; r < 4; ++r)
                wout[(size_t)(o + r) * 256 + ic] = f2bf(acc[mf][nf][r]);
        }
    }
}

// ---- big conv v4: LDS-staged A (global_load_lds dbuf) + LDS B + residual -----
// grid 1024 = [b&7 -> XCD][b_hi][pt 32][oh 2]; block: 128 o x 128 px; LDS 64 KB
__global__ void __launch_bounds__(512, 4) bigconv_mfma(const float* __restrict__ e,
                                                       const ushort* __restrict__ wbf,
                                                       float* __restrict__ out) {
    int blk = blockIdx.x;
    int ibf = blk >> 3;
    int b = (blk & 7) + 8 * (ibf >> 6);
    int rem = ibf & 63;
    int pt = rem >> 1, oh = rem & 1;
    int y0 = pt * 2;
    int tid = threadIdx.x, wid = tid >> 6, lane = tid & 63;
    int wm = wid >> 1, wn = wid & 1;     // wm: 32-o chunk, wn: out-row (px half)
    int kq = lane >> 4, l16 = lane & 15;
    __shared__ ushort Bs[4][64][64];     // 32 KB: [row][px][64ch], slot^=(px&7)
    __shared__ ushort As[2][128][64];    // 2x16 KB: [o][64i], slot^=(o&7)
    f32x4 acc[2][4];
#pragma unroll
    for (int mf = 0; mf < 2; ++mf)
#pragma unroll
        for (int nf = 0; nf < 4; ++nf) acc[mf][nf] = (f32x4){0.f, 0.f, 0.f, 0.f};
    const float* eb = e + (size_t)b * NC * NPIX;
    const ushort* wb = wbf + (size_t)b * 589824;
    const short8 zf = {};
    // ---- per-lane invariants ----
    // B-stage roles
    int c2 = tid & 31, rr = tid >> 5;
    int sr = rr >> 2, sq = rr & 3;
    int syc = min(max(y0 - 1 + sr, 0), 63);
    // A-stage per-lane source invariants (2 gl_lds per wave)
    int ao[2], asd[2];
#pragma unroll
    for (int j = 0; j < 2; ++j) {
        int du = (j * 8 + wid) * 64 + lane;
        ao[j] = du >> 3;
        asd[j] = (lane & 7) ^ (ao[j] & 7);
    }

    for (int ci = 0; ci < 4; ++ci) {
        __syncthreads();
        // ---- stage B: e NCHW f32 -> Bs bf16 (fused NHWC + swizzle) ----
        {
            const float* s0 = eb + ((size_t)(ci * 64 + 2 * c2) * 64 + syc) * 64 + sq * 16;
            const float* s1 = s0 + NPIX;
            float4 va[4], vb[4];
#pragma unroll
            for (int q = 0; q < 4; ++q) va[q] = *(const float4*)(s0 + q * 4);
#pragma unroll
            for (int q = 0; q < 4; ++q) vb[q] = *(const float4*)(s1 + q * 4);
            uint* bsrow = (uint*)&Bs[sr][0][0];
#pragma unroll
            for (int q = 0; q < 4; ++q) {
#pragma unroll
                for (int m2 = 0; m2 < 4; ++m2) {
                    int px = sq * 16 + q * 4 + m2;
                    float f0 = ((const float*)&va[q])[m2];
                    float f1 = ((const float*)&vb[q])[m2];
                    uint pk = (uint)f2bf(f0) | ((uint)f2bf(f1) << 16);
                    int s = (c2 >> 2) ^ (px & 7);
                    bsrow[px * 32 + s * 4 + (c2 & 3)] = pk;
                }
            }
        }
        // ---- stage A(tap 0) into buf 0 ----
        {
#pragma unroll
            for (int j = 0; j < 2; ++j) {
                const ushort* src = wb + (size_t)(oh * 128 + ao[j]) * 256 + ci * 64 + asd[j] * 8;
                gload_lds16(src, &As[0][0][0] + (size_t)(j * 8 + wid) * 512);
            }
        }
        __syncthreads();
        int cur = 0;
        for (int tap = 0; tap < 9; ++tap) {
            // ---- issue stage A(tap+1) into other buffer ----
            if (tap < 8) {
#pragma unroll
                for (int j = 0; j < 2; ++j) {
                    const ushort* src = wb + (size_t)(tap + 1) * 65536 +
                                        (size_t)(oh * 128 + ao[j]) * 256 + ci * 64 + asd[j] * 8;
                    gload_lds16(src, &As[cur ^ 1][0][0] + (size_t)(j * 8 + wid) * 512);
                }
            }
            // ---- compute tap from As[cur] + Bs ----
            {
                int dy = tap / 3 - 1, dx = tap % 3 - 1;
                int rl = wn + dy + 1;
                bool rowok = (unsigned)(y0 + wn + dy) < 64u;
                const ushort* bp[4]; bool ok[4]; int p7[4];
#pragma unroll
                for (int nf = 0; nf < 4; ++nf) {
                    int pxr = nf * 16 + l16 + dx;
                    ok[nf] = rowok && ((unsigned)pxr < 64u);
                    int pxc = min(max(pxr, 0), 63);
                    bp[nf] = &Bs[rl][pxc][0];
                    p7[nf] = pxc & 7;
                }
#pragma unroll
                for (int kc = 0; kc < 2; ++kc) {
                    int sd = kc * 4 + kq;
                    short8 af[2];
#pragma unroll
                    for (int mf = 0; mf < 2; ++mf) {
                        int o = wm * 32 + mf * 16 + l16;
                        af[mf] = *(const short8*)(&As[cur][o][(sd ^ (o & 7)) * 8]);
                    }
                    short8 bfr[4];
#pragma unroll
                    for (int nf = 0; nf < 4; ++nf) {
                        short8 v = *(const short8*)(bp[nf] + (sd ^ p7[nf]) * 8);
                        bfr[nf] = ok[nf] ? v : zf;
                    }
#pragma unroll
                    for (int mf = 0; mf < 2; ++mf)
#pragma unroll
                        for (int nf = 0; nf < 4; ++nf)
                            acc[mf][nf] = __builtin_amdgcn_mfma_f32_16x16x32_bf16(af[mf], bfr[nf], acc[mf][nf], 0, 0, 0);
                }
            }
            __syncthreads();
            cur ^= 1;
        }
    }
    // ---- epilogue: + residual ----
    int pcol0 = pt * 128 + wn * 64 + l16;
    float* ob = out + (size_t)b * NC * NPIX;
#pragma unroll
    for (int mf = 0; mf < 2; ++mf) {
        int o = oh * 128 + wm * 32 + mf * 16 + kq * 4;
#pragma unroll
        for (int nf = 0; nf < 4; ++nf) {
            int p = pcol0 + nf * 16;
#pragma unroll
            for (int r = 0; r < 4; ++r) {
                size_t idx = (size_t)(o + r) * NPIX + p;
                ob[idx] = acc[mf][nf][r] + eb[idx];
            }
        }
    }
}

extern "C" void kernel_launch(void* const* d_in, const int* in_sizes, int n_in,
                              void* d_out, int out_size, void* d_ws, size_t ws_size,
                              hipStream_t stream) {
    const float* e   = (const float*)d_in[0];
    const float* pam = (const float*)d_in[1];
    const float* qw  = (const float*)d_in[2];
    const float* kw  = (const float*)d_in[3];
    const float* vw  = (const float*)d_in[4];
    const float* pw  = (const float*)d_in[5];
    float* out = (float*)d_out;
    float* ws  = (float*)d_ws;

    // layout (f32-slot offsets), total ~26.7 MB:
    ushort* wbf  = (ushort*)ws;                      // 9,437,184 ushorts (18.9MB)
    float*  S    = ws + 4718592;
    ushort* maxeT = (ushort*)S;                      // 1,048,576 ushorts
    ushort* pamT  = (ushort*)(S + 524288);           // 1,048,576 ushorts
    ushort* wqT   = (ushort*)(S + 1048576);          // 589,824 ushorts
    ushort* wkT   = (ushort*)(S + 1343488);          // 589,824 ushorts
    ushort* pbf   = (ushort*)(S + 1638400);          // 65,536 ushorts
    ushort* vwT   = (ushort*)(S + 1671168);          // 589,824 ushorts
    // reuse: qb/kTb inside wbf region (dead before weff writes it)
    ushort* qb    = (ushort*)ws;                     // 1,048,576 ushorts
    ushort* kTb   = (ushort*)(ws + 524288);          // 1,048,576 ushorts
    ushort* attnT = maxeT;                           // reuse (dead after conv16)
    ushort* Mbf   = pamT;                            // reuse (dead after conv16)

    prep_k<<<1104, 256, 0, stream>>>(e, pam, qw, kw, vw, pw,
                                     maxeT, pamT, wqT, wkT, pbf, vwT);
    conv16_mfma<<<128, 512, 0, stream>>>(maxeT, pamT, wqT, wkT, qb, kTb);
    attn_mfma<<<64, 512, 0, stream>>>(qb, kTb, attnT);
    mproj_mfma<<<64, 512, 0, stream>>>(pbf, attnT, Mbf);
    weff_mfma<<<256, 512, 0, stream>>>(Mbf, vwT, wbf);
    bigconv_mfma<<<1024, 512, 0, stream>>>(e, wbf, out);
}

// Round 7
// 212.646 us; speedup vs baseline: 11.0757x; 1.5317x over previous
//
#include <hip/hip_runtime.h>
#include <hip/hip_bf16.h>

#define NB 16
#define NC 256
#define NPIX 4096

typedef __attribute__((ext_vector_type(8))) short short8;
typedef __attribute__((ext_vector_type(4))) short short4v;
typedef __attribute__((ext_vector_type(4))) float f32x4;

static __device__ __forceinline__ ushort f2bf(float f) {
    __hip_bfloat16 h = __float2bfloat16(f);
    return *(ushort*)&h;
}

static __device__ __forceinline__ void gload_lds16(const ushort* g, ushort* l) {
    __builtin_amdgcn_global_load_lds(
        (const __attribute__((address_space(1))) unsigned int*)g,
        (__attribute__((address_space(3))) unsigned int*)l, 16, 0, 0);
}

// ================= prep: input-only transforms + norm zeroing =================
// blocks: [0,256) pooltr | [256,512) pamtr | [512,1024) wtap q/k |
//         [1024,1040) projcast | [1040,1104) vw transpose | 1104 zero norms
__global__ void __launch_bounds__(256) prep_k(
    const float* __restrict__ e, const float* __restrict__ pam,
    const float* __restrict__ qw, const float* __restrict__ kw,
    const float* __restrict__ vw, const float* __restrict__ pw,
    ushort* __restrict__ maxeT, ushort* __restrict__ pamT,
    ushort* __restrict__ wqT, ushort* __restrict__ wkT,
    ushort* __restrict__ pbf, ushort* __restrict__ vwT,
    float* __restrict__ qnorm, float* __restrict__ knorm) {
    __shared__ float smem[9216];   // 36 KB max across branches
    int blk = blockIdx.x, t = threadIdx.x;
    if (blk < 512) {
        int isPam = blk >> 8;
        int bb = blk & 255;
        int b = bb >> 4, cg = bb & 15;
        float (*lt)[256] = (float(*)[256])smem;
        if (!isPam) {
            int py = t >> 4, px = t & 15;
#pragma unroll
            for (int cc = 0; cc < 16; ++cc) {
                int c = cg * 16 + cc;
                const float* p = e + (size_t)(b * 256 + c) * NPIX;
                float s = 0.f;
#pragma unroll
                for (int r = 0; r < 4; ++r) {
                    float4 v = *(const float4*)(p + (py * 4 + r) * 64 + px * 4);
                    s += v.x + v.y + v.z + v.w;
                }
                lt[cc][t] = s * 0.0625f;
            }
        } else {
#pragma unroll
            for (int cc = 0; cc < 16; ++cc)
                lt[cc][t] = pam[(size_t)(b * 256 + cg * 16 + cc) * 256 + t];
        }
        __syncthreads();
        ushort* dstb = (isPam ? pamT : maxeT) + (size_t)b * 65536 + (size_t)t * 256 + cg * 16;
#pragma unroll
        for (int g = 0; g < 2; ++g) {
            short8 v;
#pragma unroll
            for (int k = 0; k < 8; ++k) v[k] = (short)f2bf(lt[g * 8 + k][t]);
            *(short8*)(dstb + g * 8) = v;
        }
    } else if (blk < 1024) {
        int idx = blk - 512;
        const float* src = (idx < 256) ? qw : kw;
        ushort* dst = (idx < 256) ? wqT : wkT;
        int o = idx & 255;
        float wv[9];
#pragma unroll
        for (int j = 0; j < 9; ++j) wv[j] = src[(size_t)o * 2304 + t * 9 + j];
#pragma unroll
        for (int j = 0; j < 9; ++j) dst[(size_t)j * 65536 + (size_t)o * 256 + t] = f2bf(wv[j]);
    } else if (blk < 1040) {
        int base = (blk - 1024) * 4096;
        for (int g = 0; g < 16; ++g) {
            int idx = base + g * 256 + t;
            pbf[idx] = f2bf(pw[idx]);
        }
    } else if (blk < 1104) {
        int d0 = (blk - 1040) * 4;
        float* lt = smem;   // flat [4][2304]
        for (int u = 0; u < 36; ++u) lt[u * 256 + t] = vw[(size_t)d0 * 2304 + u * 256 + t];
        __syncthreads();
#pragma unroll
        for (int r = 0; r < 9; ++r) {
            int idx = r * 256 + t;
            int i = idx / 9, j = idx % 9;
            short4v v;
#pragma unroll
            for (int dd = 0; dd < 4; ++dd) v[dd] = (short)f2bf(lt[dd * 2304 + idx]);
            *(short4v*)(vwT + ((size_t)(j * 256 + i)) * 256 + d0) = v;
        }
    } else {
        // zero qnorm/knorm [16][256] each
        for (int g = 0; g < 16; ++g) {
            qnorm[g * 256 + t] = 0.f;
            knorm[g * 256 + t] = 0.f;
        }
    }
}

// ---- conv16 v2: LDS-staged B (once) + pipelined A chunks; unnormalized out ---
// grid 512 = qk(2) x b(16) x og(4) x tg(4); block 256 thr (4 waves, 32o x 32tok each)
// out[o][n] bf16 + atomicAdd per-row sumsq into q/k norm arrays
__global__ void __launch_bounds__(256, 2) conv16_mfma(const ushort* __restrict__ maxeT,
                                                      const ushort* __restrict__ pamT,
                                                      const ushort* __restrict__ wqT,
                                                      const ushort* __restrict__ wkT,
                                                      ushort* __restrict__ qb,
                                                      ushort* __restrict__ kTb,
                                                      float* __restrict__ qnorm,
                                                      float* __restrict__ knorm) {
    int blk = blockIdx.x;
    int qk = blk >> 8;
    int b  = (blk >> 4) & 15;
    int og = (blk >> 2) & 3;
    int tg = blk & 3;
    const ushort* inT = qk ? pamT : maxeT;
    const ushort* wt  = qk ? wkT : wqT;
    ushort* outp      = qk ? kTb : qb;
    float* nrm        = qk ? knorm : qnorm;
    int tid = threadIdx.x, wid = tid >> 6, lane = tid & 63;
    int wm = wid >> 1, wn = wid & 1;
    int kq = lane >> 4, l16 = lane & 15;
    int ty0 = tg * 4;
    __shared__ ushort Bs[96][256];   // 48 KB: 6 token-rows x 16 tok x 256 ch, unit^=(tok&7)
    __shared__ ushort As[2][64][64]; // 16 KB dbuf: 64 o x 64 i, unit^=(o&7)
    const ushort* itb = inT + (size_t)b * 65536;
    // ---- stage B once (pre-swizzled source, linear LDS dest) ----
    {
#pragma unroll
        for (int j = 0; j < 12; ++j) {
            int d = (j * 4 + wid) * 64 + lane;
            int tok = d >> 5, u = d & 31;
            int lr = tok >> 4, tx = tok & 15;
            int gy = min(max(ty0 - 1 + lr, 0), 15);
            gload_lds16(itb + (gy * 16 + tx) * 256 + ((u ^ (tok & 7)) * 8),
                        &Bs[0][0] + (size_t)(j * 4 + wid) * 512);
        }
    }
    // ---- A staging invariants + pipeline ----
    int aoff[2];
#pragma unroll
    for (int j = 0; j < 2; ++j) {
        int d = (j * 4 + wid) * 64 + lane;
        int o = d >> 3, u = d & 7;
        aoff[j] = (og * 64 + o) * 256 + ((u ^ (o & 7)) * 8);
    }
    auto stageA = [&](int s, int buf) {
        const ushort* base = wt + (size_t)(s >> 2) * 65536 + (s & 3) * 64;
#pragma unroll
        for (int j = 0; j < 2; ++j)
            gload_lds16(base + aoff[j], &As[buf][0][0] + (size_t)(j * 4 + wid) * 512);
    };
    stageA(0, 0);
    stageA(1, 1);
    __syncthreads();
    f32x4 acc[2][2];
#pragma unroll
    for (int mf = 0; mf < 2; ++mf)
#pragma unroll
        for (int nf = 0; nf < 2; ++nf) acc[mf][nf] = (f32x4){0.f, 0.f, 0.f, 0.f};
    const short8 zf = {};
    for (int s = 0; s < 36; ++s) {
        int tap = s >> 2, kh = s & 3;
        int dy = tap / 3 - 1, dx = tap % 3 - 1;
        const ushort* bp[2]; bool ok[2]; int lt7[2];
#pragma unroll
        for (int nf = 0; nf < 2; ++nf) {
            int n = tg * 64 + wn * 32 + nf * 16 + l16;
            int ny = (n >> 4) + dy, nx = (n & 15) + dx;
            ok[nf] = ((unsigned)ny < 16u) && ((unsigned)nx < 16u);
            int lrc = min(max(ny - ty0 + 1, 0), 5);
            int nxc = min(max(nx, 0), 15);
            int ltok = lrc * 16 + nxc;
            bp[nf] = &Bs[ltok][0];
            lt7[nf] = ltok & 7;
        }
#pragma unroll
        for (int kc = 0; kc < 2; ++kc) {
            int ua = kc * 4 + kq;
            int ub = kh * 8 + kc * 4 + kq;
            short8 af[2], bfr[2];
#pragma unroll
            for (int mf = 0; mf < 2; ++mf) {
                int o = wm * 32 + mf * 16 + l16;
                af[mf] = *(const short8*)(&As[s & 1][o][(ua ^ (o & 7)) * 8]);
            }
#pragma unroll
            for (int nf = 0; nf < 2; ++nf) {
                short8 v = *(const short8*)(bp[nf] + ((ub ^ lt7[nf]) * 8));
                bfr[nf] = ok[nf] ? v : zf;
            }
#pragma unroll
            for (int mf = 0; mf < 2; ++mf)
#pragma unroll
                for (int nf = 0; nf < 2; ++nf)
                    acc[mf][nf] = __builtin_amdgcn_mfma_f32_16x16x32_bf16(af[mf], bfr[nf], acc[mf][nf], 0, 0, 0);
        }
        __syncthreads();
        if (s + 2 < 36) stageA(s + 2, s & 1);
    }
    // ---- per-row sumsq partials -> atomicAdd ----
    float ss[2][4];
#pragma unroll
    for (int mf = 0; mf < 2; ++mf)
#pragma unroll
        for (int r = 0; r < 4; ++r) ss[mf][r] = 0.f;
#pragma unroll
    for (int mf = 0; mf < 2; ++mf)
#pragma unroll
        for (int nf = 0; nf < 2; ++nf)
#pragma unroll
            for (int r = 0; r < 4; ++r) ss[mf][r] += acc[mf][nf][r] * acc[mf][nf][r];
#pragma unroll
    for (int mf = 0; mf < 2; ++mf)
#pragma unroll
        for (int r = 0; r < 4; ++r) {
#pragma unroll
            for (int off = 1; off < 16; off <<= 1) ss[mf][r] += __shfl_xor(ss[mf][r], off, 64);
        }
    if (l16 == 0) {
#pragma unroll
        for (int mf = 0; mf < 2; ++mf)
#pragma unroll
            for (int r = 0; r < 4; ++r)
                atomicAdd(&nrm[b * 256 + og * 64 + wm * 32 + mf * 16 + kq * 4 + r], ss[mf][r]);
    }
    // ---- write unnormalized bf16 out[o][n] ----
    ushort* ob = outp + (size_t)b * 65536;
#pragma unroll
    for (int mf = 0; mf < 2; ++mf)
#pragma unroll
        for (int nf = 0; nf < 2; ++nf) {
            int col = tg * 64 + wn * 32 + nf * 16 + l16;
#pragma unroll
            for (int r = 0; r < 4; ++r) {
                int row = og * 64 + wm * 32 + mf * 16 + kq * 4 + r;
                ob[(size_t)row * 256 + col] = f2bf(acc[mf][nf][r]);
            }
        }
}

// ---- attn via MFMA + norms + softmax; 64 blocks; attnT[d][c] bf16 ------------
__global__ void __launch_bounds__(512) attn_mfma(const ushort* __restrict__ qb,
                                                 const ushort* __restrict__ kTb,
                                                 const float* __restrict__ qnorm,
                                                 const float* __restrict__ knorm,
                                                 ushort* __restrict__ attnT) {
    int blk = blockIdx.x;
    int b = (blk & 7) + 8 * ((blk >> 3) & 1);
    int cg = blk >> 4;
    int tid = threadIdx.x, wid = tid >> 6, lane = tid & 63;
    int rw = wid & 3, chf = wid >> 2;
    int kq = lane >> 4, l16 = lane & 15;
    int c0w = cg * 64 + rw * 16;
    int lrow = rw * 16 + kq * 4;
    f32x4 acc[8];
#pragma unroll
    for (int nf = 0; nf < 8; ++nf) acc[nf] = (f32x4){0.f, 0.f, 0.f, 0.f};
    const ushort* qp = qb + (size_t)b * 65536;
    const ushort* kp = kTb + (size_t)b * 65536 + (size_t)(chf * 128) * 256;
    for (int kc = 0; kc < 8; ++kc) {
        short8 af = *(const short8*)(qp + (size_t)(c0w + l16) * 256 + kc * 32 + kq * 8);
#pragma unroll
        for (int nf = 0; nf < 8; ++nf) {
            short8 bf = *(const short8*)(kp + (size_t)(nf * 16 + l16) * 256 + kc * 32 + kq * 8);
            acc[nf] = __builtin_amdgcn_mfma_f32_16x16x32_bf16(af, bf, acc[nf], 0, 0, 0);
        }
    }
    // apply 1/16 and the deferred L2 norms to the logits
    float rq[4], rk[8];
#pragma unroll
    for (int r = 0; r < 4; ++r)
        rq[r] = rsqrtf(fmaxf(qnorm[b * 256 + c0w + kq * 4 + r], 1e-24f)) * 0.0625f;
#pragma unroll
    for (int nf = 0; nf < 8; ++nf)
        rk[nf] = rsqrtf(fmaxf(knorm[b * 256 + chf * 128 + nf * 16 + l16], 1e-24f));
#pragma unroll
    for (int nf = 0; nf < 8; ++nf)
#pragma unroll
        for (int r = 0; r < 4; ++r) acc[nf][r] *= rq[r] * rk[nf];
    __shared__ float red[64][2];
    float m4[4], s4[4];
#pragma unroll
    for (int r = 0; r < 4; ++r) {
        float m = -1e30f;
#pragma unroll
        for (int nf = 0; nf < 8; ++nf) m = fmaxf(m, acc[nf][r]);
#pragma unroll
        for (int off = 1; off < 16; off <<= 1) m = fmaxf(m, __shfl_xor(m, off, 64));
        m4[r] = m;
    }
    if (l16 == 0) {
#pragma unroll
        for (int r = 0; r < 4; ++r) red[lrow + r][chf] = m4[r];
    }
    __syncthreads();
#pragma unroll
    for (int r = 0; r < 4; ++r) m4[r] = fmaxf(red[lrow + r][0], red[lrow + r][1]);
    __syncthreads();
#pragma unroll
    for (int r = 0; r < 4; ++r) {
        float s = 0.f;
#pragma unroll
        for (int nf = 0; nf < 8; ++nf) {
            float ex = __expf(acc[nf][r] - m4[r]);
            acc[nf][r] = ex;
            s += ex;
        }
#pragma unroll
        for (int off = 1; off < 16; off <<= 1) s += __shfl_xor(s, off, 64);
        s4[r] = s;
    }
    if (l16 == 0) {
#pragma unroll
        for (int r = 0; r < 4; ++r) red[lrow + r][chf] = s4[r];
    }
    __syncthreads();
#pragma unroll
    for (int r = 0; r < 4; ++r) {
        float inv = 1.0f / (red[lrow + r][0] + red[lrow + r][1]);
#pragma unroll
        for (int nf = 0; nf < 8; ++nf) acc[nf][r] *= inv;
    }
    ushort* ap = attnT + (size_t)b * 65536;
#pragma unroll
    for (int nf = 0; nf < 8; ++nf) {
        int d = chf * 128 + nf * 16 + l16;
        short4v v;
#pragma unroll
        for (int r = 0; r < 4; ++r) v[r] = (short)f2bf(acc[nf][r]);
        *(short4v*)(ap + (size_t)d * 256 + c0w + kq * 4) = v;
    }
}

// ---- Mbf[b][o][d] = bf16( sum_c pbf[o,c] * attnT[d,c] ); 64 blocks -----------
__global__ void __launch_bounds__(512) mproj_mfma(const ushort* __restrict__ pbf,
                                                  const ushort* __restrict__ attnT,
                                                  ushort* __restrict__ Mbf) {
    int blk = blockIdx.x;
    int b = (blk & 7) + 8 * ((blk >> 3) & 1);
    int og = blk >> 4;
    int tid = threadIdx.x, wid = tid >> 6, lane = tid & 63;
    int rw = wid & 3, chf = wid >> 2;
    int kq = lane >> 4, l16 = lane & 15;
    int o0w = og * 64 + rw * 16;
    f32x4 acc[8];
#pragma unroll
    for (int nf = 0; nf < 8; ++nf) acc[nf] = (f32x4){0.f, 0.f, 0.f, 0.f};
    const ushort* ap = attnT + (size_t)b * 65536 + (size_t)(chf * 128) * 256;
    for (int kc = 0; kc < 8; ++kc) {
        short8 af = *(const short8*)(pbf + (size_t)(o0w + l16) * 256 + kc * 32 + kq * 8);
#pragma unroll
        for (int nf = 0; nf < 8; ++nf) {
            short8 bf = *(const short8*)(ap + (size_t)(nf * 16 + l16) * 256 + kc * 32 + kq * 8);
            acc[nf] = __builtin_amdgcn_mfma_f32_16x16x32_bf16(af, bf, acc[nf], 0, 0, 0);
        }
    }
    ushort* mb = Mbf + (size_t)b * 65536;
#pragma unroll
    for (int nf = 0; nf < 8; ++nf)
#pragma unroll
        for (int r = 0; r < 4; ++r)
            mb[(size_t)(o0w + kq * 4 + r) * 256 + chf * 128 + nf * 16 + l16] = f2bf(acc[nf][r]);
}

// ---- wbf[b][j][o][i] = bf16( sum_d Mbf[b,o,d] * vwT[j,i,d] ) via MFMA --------
__global__ void __launch_bounds__(512) weff_mfma(const ushort* __restrict__ Mbf,
                                                 const ushort* __restrict__ vwT,
                                                 ushort* __restrict__ wbf) {
    int blk = blockIdx.x;            // 256 blocks, XCD-swizzled; j>=9 idle
    int i = blk >> 3;
    int b = (blk & 7) + 8 * (i >> 4);
    int j = i & 15;
    if (j >= 9) return;
    int tid = threadIdx.x;
    int wid = tid >> 6, lane = tid & 63;
    int wm = wid >> 1, wn = wid & 1;
    int kq = lane >> 4, l16 = lane & 15;
    f32x4 acc[4][8];
#pragma unroll
    for (int mf = 0; mf < 4; ++mf)
#pragma unroll
        for (int nf = 0; nf < 8; ++nf) acc[mf][nf] = (f32x4){0.f, 0.f, 0.f, 0.f};
    const ushort* abase = Mbf + (size_t)b * 65536 + (size_t)(wm * 64 + l16) * 256 + kq * 8;
    const ushort* bbase = vwT + (size_t)(j * 256 + wn * 128 + l16) * 256 + kq * 8;
    for (int kc = 0; kc < 8; ++kc) {
        int d0 = kc * 32;
        short8 af[4], bfr[8];
#pragma unroll
        for (int mf = 0; mf < 4; ++mf) af[mf] = *(const short8*)(abase + mf * 16 * 256 + d0);
#pragma unroll
        for (int nf = 0; nf < 8; ++nf) bfr[nf] = *(const short8*)(bbase + nf * 16 * 256 + d0);
#pragma unroll
        for (int mf = 0; mf < 4; ++mf)
#pragma unroll
            for (int nf = 0; nf < 8; ++nf)
                acc[mf][nf] = __builtin_amdgcn_mfma_f32_16x16x32_bf16(af[mf], bfr[nf], acc[mf][nf], 0, 0, 0);
    }
    ushort* wout = wbf + ((size_t)(b * 9 + j)) * 65536;
#pragma unroll
    for (int mf = 0; mf < 4; ++mf) {
        int o = wm * 64 + mf * 16 + kq * 4;
#pragma unroll
        for (int nf = 0; nf < 8; ++nf) {
            int ic = wn * 128 + nf * 16 + l16;
#pragma unroll
            for (int r = 0; r < 4; ++r)
                wout[(size_t)(o + r) * 256 + ic] = f2bf(acc[mf][nf][r]);
        }
    }
}

// ---- big conv v4: LDS-staged A (global_load_lds dbuf) + LDS B + residual -----
__global__ void __launch_bounds__(512, 4) bigconv_mfma(const float* __restrict__ e,
                                                       const ushort* __restrict__ wbf,
                                                       float* __restrict__ out) {
    int blk = blockIdx.x;
    int ibf = blk >> 3;
    int b = (blk & 7) + 8 * (ibf >> 6);
    int rem = ibf & 63;
    int pt = rem >> 1, oh = rem & 1;
    int y0 = pt * 2;
    int tid = threadIdx.x, wid = tid >> 6, lane = tid & 63;
    int wm = wid >> 1, wn = wid & 1;
    int kq = lane >> 4, l16 = lane & 15;
    __shared__ ushort Bs[4][64][64];
    __shared__ ushort As[2][128][64];
    f32x4 acc[2][4];
#pragma unroll
    for (int mf = 0; mf < 2; ++mf)
#pragma unroll
        for (int nf = 0; nf < 4; ++nf) acc[mf][nf] = (f32x4){0.f, 0.f, 0.f, 0.f};
    const float* eb = e + (size_t)b * NC * NPIX;
    const ushort* wb = wbf + (size_t)b * 589824;
    const short8 zf = {};
    int c2 = tid & 31, rr = tid >> 5;
    int sr = rr >> 2, sq = rr & 3;
    int syc = min(max(y0 - 1 + sr, 0), 63);
    int ao[2], asd[2];
#pragma unroll
    for (int j = 0; j < 2; ++j) {
        int du = (j * 8 + wid) * 64 + lane;
        ao[j] = du >> 3;
        asd[j] = (lane & 7) ^ (ao[j] & 7);
    }

    for (int ci = 0; ci < 4; ++ci) {
        __syncthreads();
        {
            const float* s0 = eb + ((size_t)(ci * 64 + 2 * c2) * 64 + syc) * 64 + sq * 16;
            const float* s1 = s0 + NPIX;
            float4 va[4], vb[4];
#pragma unroll
            for (int q = 0; q < 4; ++q) va[q] = *(const float4*)(s0 + q * 4);
#pragma unroll
            for (int q = 0; q < 4; ++q) vb[q] = *(const float4*)(s1 + q * 4);
            uint* bsrow = (uint*)&Bs[sr][0][0];
#pragma unroll
            for (int q = 0; q < 4; ++q) {
#pragma unroll
                for (int m2 = 0; m2 < 4; ++m2) {
                    int px = sq * 16 + q * 4 + m2;
                    float f0 = ((const float*)&va[q])[m2];
                    float f1 = ((const float*)&vb[q])[m2];
                    uint pk = (uint)f2bf(f0) | ((uint)f2bf(f1) << 16);
                    int s = (c2 >> 2) ^ (px & 7);
                    bsrow[px * 32 + s * 4 + (c2 & 3)] = pk;
                }
            }
        }
        {
#pragma unroll
            for (int j = 0; j < 2; ++j) {
                const ushort* src = wb + (size_t)(oh * 128 + ao[j]) * 256 + ci * 64 + asd[j] * 8;
                gload_lds16(src, &As[0][0][0] + (size_t)(j * 8 + wid) * 512);
            }
        }
        __syncthreads();
        int cur = 0;
        for (int tap = 0; tap < 9; ++tap) {
            if (tap < 8) {
#pragma unroll
                for (int j = 0; j < 2; ++j) {
                    const ushort* src = wb + (size_t)(tap + 1) * 65536 +
                                        (size_t)(oh * 128 + ao[j]) * 256 + ci * 64 + asd[j] * 8;
                    gload_lds16(src, &As[cur ^ 1][0][0] + (size_t)(j * 8 + wid) * 512);
                }
            }
            {
                int dy = tap / 3 - 1, dx = tap % 3 - 1;
                int rl = wn + dy + 1;
                bool rowok = (unsigned)(y0 + wn + dy) < 64u;
                const ushort* bp[4]; bool ok[4]; int p7[4];
#pragma unroll
                for (int nf = 0; nf < 4; ++nf) {
                    int pxr = nf * 16 + l16 + dx;
                    ok[nf] = rowok && ((unsigned)pxr < 64u);
                    int pxc = min(max(pxr, 0), 63);
                    bp[nf] = &Bs[rl][pxc][0];
                    p7[nf] = pxc & 7;
                }
#pragma unroll
                for (int kc = 0; kc < 2; ++kc) {
                    int sd = kc * 4 + kq;
                    short8 af[2];
#pragma unroll
                    for (int mf = 0; mf < 2; ++mf) {
                        int o = wm * 32 + mf * 16 + l16;
                        af[mf] = *(const short8*)(&As[cur][o][(sd ^ (o & 7)) * 8]);
                    }
                    short8 bfr[4];
#pragma unroll
                    for (int nf = 0; nf < 4; ++nf) {
                        short8 v = *(const short8*)(bp[nf] + (sd ^ p7[nf]) * 8);
                        bfr[nf] = ok[nf] ? v : zf;
                    }
#pragma unroll
                    for (int mf = 0; mf < 2; ++mf)
#pragma unroll
                        for (int nf = 0; nf < 4; ++nf)
                            acc[mf][nf] = __builtin_amdgcn_mfma_f32_16x16x32_bf16(af[mf], bfr[nf], acc[mf][nf], 0, 0, 0);
                }
            }
            __syncthreads();
            cur ^= 1;
        }
    }
    int pcol0 = pt * 128 + wn * 64 + l16;
    float* ob = out + (size_t)b * NC * NPIX;
#pragma unroll
    for (int mf = 0; mf < 2; ++mf) {
        int o = oh * 128 + wm * 32 + mf * 16 + kq * 4;
#pragma unroll
        for (int nf = 0; nf < 4; ++nf) {
            int p = pcol0 + nf * 16;
#pragma unroll
            for (int r = 0; r < 4; ++r) {
                size_t idx = (size_t)(o + r) * NPIX + p;
                ob[idx] = acc[mf][nf][r] + eb[idx];
            }
        }
    }
}

extern "C" void kernel_launch(void* const* d_in, const int* in_sizes, int n_in,
                              void* d_out, int out_size, void* d_ws, size_t ws_size,
                              hipStream_t stream) {
    const float* e   = (const float*)d_in[0];
    const float* pam = (const float*)d_in[1];
    const float* qw  = (const float*)d_in[2];
    const float* kw  = (const float*)d_in[3];
    const float* vw  = (const float*)d_in[4];
    const float* pw  = (const float*)d_in[5];
    float* out = (float*)d_out;
    float* ws  = (float*)d_ws;

    // layout (f32-slot offsets), total ~26.8 MB:
    ushort* wbf  = (ushort*)ws;                      // 9,437,184 ushorts (18.9MB)
    float*  S    = ws + 4718592;
    ushort* maxeT = (ushort*)S;                      // 1,048,576 ushorts
    ushort* pamT  = (ushort*)(S + 524288);           // 1,048,576 ushorts
    ushort* wqT   = (ushort*)(S + 1048576);          // 589,824 ushorts
    ushort* wkT   = (ushort*)(S + 1343488);          // 589,824 ushorts
    ushort* pbf   = (ushort*)(S + 1638400);          // 65,536 ushorts
    ushort* vwT   = (ushort*)(S + 1671168);          // 589,824 ushorts
    float*  qnorm = S + 1966080;                     // 4096 f32
    float*  knorm = S + 1970176;                     // 4096 f32
    // reuse: qb/kTb inside wbf region (dead before weff writes it)
    ushort* qb    = (ushort*)ws;                     // 1,048,576 ushorts
    ushort* kTb   = (ushort*)(ws + 524288);          // 1,048,576 ushorts
    ushort* attnT = maxeT;                           // reuse (dead after conv16)
    ushort* Mbf   = pamT;                            // reuse (dead after conv16)

    prep_k<<<1105, 256, 0, stream>>>(e, pam, qw, kw, vw, pw,
                                     maxeT, pamT, wqT, wkT, pbf, vwT, qnorm, knorm);
    conv16_mfma<<<512, 256, 0, stream>>>(maxeT, pamT, wqT, wkT, qb, kTb, qnorm, knorm);
    attn_mfma<<<64, 512, 0, stream>>>(qb, kTb, qnorm, knorm, attnT);
    mproj_mfma<<<64, 512, 0, stream>>>(pbf, attnT, Mbf);
    weff_mfma<<<256, 512, 0, stream>>>(Mbf, vwT, wbf);
    bigconv_mfma<<<1024, 512, 0, stream>>>(e, wbf, out);
}

// Round 8
// 204.376 us; speedup vs baseline: 11.5239x; 1.0405x over previous
//
#include <hip/hip_runtime.h>
#include <hip/hip_bf16.h>

#define NB 16
#define NC 256
#define NPIX 4096

typedef __attribute__((ext_vector_type(8))) short short8;
typedef __attribute__((ext_vector_type(4))) short short4v;
typedef __attribute__((ext_vector_type(4))) float f32x4;

static __device__ __forceinline__ ushort f2bf(float f) {
    __hip_bfloat16 h = __float2bfloat16(f);
    return *(ushort*)&h;
}

static __device__ __forceinline__ void gload_lds16(const ushort* g, ushort* l) {
    __builtin_amdgcn_global_load_lds(
        (const __attribute__((address_space(1))) unsigned int*)g,
        (__attribute__((address_space(3))) unsigned int*)l, 16, 0, 0);
}

// ================= prep: input-only transforms + norm zeroing =================
// blocks: [0,1024) pool (reg-direct, 4ch/blk) | [1024,1280) pamtr |
// [1280,1792) wtap | [1792,1808) projcast | [1808,1872) vwT | 1872 zero norms
__global__ void __launch_bounds__(256) prep_k(
    const float* __restrict__ e, const float* __restrict__ pam,
    const float* __restrict__ qw, const float* __restrict__ kw,
    const float* __restrict__ vw, const float* __restrict__ pw,
    ushort* __restrict__ maxeT, ushort* __restrict__ pamT,
    ushort* __restrict__ wqT, ushort* __restrict__ wkT,
    ushort* __restrict__ pbf, ushort* __restrict__ vwT,
    float* __restrict__ qnorm, float* __restrict__ knorm) {
    __shared__ float smem[9216];
    int blk = blockIdx.x, t = threadIdx.x;
    if (blk < 1024) {
        // pool(e) -> maxeT[b][tok][c] bf16; 4 channels per block, no LDS
        int b = blk >> 6, c0 = (blk & 63) * 4;
        int py = t >> 4, px4 = (t & 15) * 4;
        float s[4];
#pragma unroll
        for (int cc = 0; cc < 4; ++cc) {
            const float* p = e + (size_t)(b * 256 + c0 + cc) * NPIX;
            float a = 0.f;
#pragma unroll
            for (int r = 0; r < 4; ++r) {
                float4 v = *(const float4*)(p + (py * 4 + r) * 64 + px4);
                a += v.x + v.y + v.z + v.w;
            }
            s[cc] = a * 0.0625f;
        }
        short4v v;
#pragma unroll
        for (int cc = 0; cc < 4; ++cc) v[cc] = (short)f2bf(s[cc]);
        *(short4v*)(maxeT + (size_t)b * 65536 + (size_t)t * 256 + c0) = v;
    } else if (blk < 1280) {
        int bb = blk - 1024;
        int b = bb >> 4, cg = bb & 15;
        float (*lt)[256] = (float(*)[256])smem;
#pragma unroll
        for (int cc = 0; cc < 16; ++cc)
            lt[cc][t] = pam[(size_t)(b * 256 + cg * 16 + cc) * 256 + t];
        __syncthreads();
        ushort* dstb = pamT + (size_t)b * 65536 + (size_t)t * 256 + cg * 16;
#pragma unroll
        for (int g = 0; g < 2; ++g) {
            short8 v;
#pragma unroll
            for (int k = 0; k < 8; ++k) v[k] = (short)f2bf(lt[g * 8 + k][t]);
            *(short8*)(dstb + g * 8) = v;
        }
    } else if (blk < 1792) {
        int idx = blk - 1280;
        const float* src = (idx < 256) ? qw : kw;
        ushort* dst = (idx < 256) ? wqT : wkT;
        int o = idx & 255;
        float wv[9];
#pragma unroll
        for (int j = 0; j < 9; ++j) wv[j] = src[(size_t)o * 2304 + t * 9 + j];
#pragma unroll
        for (int j = 0; j < 9; ++j) dst[(size_t)j * 65536 + (size_t)o * 256 + t] = f2bf(wv[j]);
    } else if (blk < 1808) {
        int base = (blk - 1792) * 4096;
        for (int g = 0; g < 16; ++g) {
            int idx = base + g * 256 + t;
            pbf[idx] = f2bf(pw[idx]);
        }
    } else if (blk < 1872) {
        int d0 = (blk - 1808) * 4;
        float* lt = smem;   // flat [4][2304]
        for (int u = 0; u < 36; ++u) lt[u * 256 + t] = vw[(size_t)d0 * 2304 + u * 256 + t];
        __syncthreads();
#pragma unroll
        for (int r = 0; r < 9; ++r) {
            int idx = r * 256 + t;
            int i = idx / 9, j = idx % 9;
            short4v v;
#pragma unroll
            for (int dd = 0; dd < 4; ++dd) v[dd] = (short)f2bf(lt[dd * 2304 + idx]);
            *(short4v*)(vwT + ((size_t)(j * 256 + i)) * 256 + d0) = v;
        }
    } else {
        for (int g = 0; g < 16; ++g) {
            qnorm[g * 256 + t] = 0.f;
            knorm[g * 256 + t] = 0.f;
        }
    }
}

// ---- conv16 v2: LDS-staged B (once) + pipelined A chunks; unnormalized out ---
__global__ void __launch_bounds__(256, 2) conv16_mfma(const ushort* __restrict__ maxeT,
                                                      const ushort* __restrict__ pamT,
                                                      const ushort* __restrict__ wqT,
                                                      const ushort* __restrict__ wkT,
                                                      ushort* __restrict__ qb,
                                                      ushort* __restrict__ kTb,
                                                      float* __restrict__ qnorm,
                                                      float* __restrict__ knorm) {
    int blk = blockIdx.x;
    int qk = blk >> 8;
    int b  = (blk >> 4) & 15;
    int og = (blk >> 2) & 3;
    int tg = blk & 3;
    const ushort* inT = qk ? pamT : maxeT;
    const ushort* wt  = qk ? wkT : wqT;
    ushort* outp      = qk ? kTb : qb;
    float* nrm        = qk ? knorm : qnorm;
    int tid = threadIdx.x, wid = tid >> 6, lane = tid & 63;
    int wm = wid >> 1, wn = wid & 1;
    int kq = lane >> 4, l16 = lane & 15;
    int ty0 = tg * 4;
    __shared__ ushort Bs[96][256];
    __shared__ ushort As[2][64][64];
    const ushort* itb = inT + (size_t)b * 65536;
    {
#pragma unroll
        for (int j = 0; j < 12; ++j) {
            int d = (j * 4 + wid) * 64 + lane;
            int tok = d >> 5, u = d & 31;
            int lr = tok >> 4, tx = tok & 15;
            int gy = min(max(ty0 - 1 + lr, 0), 15);
            gload_lds16(itb + (gy * 16 + tx) * 256 + ((u ^ (tok & 7)) * 8),
                        &Bs[0][0] + (size_t)(j * 4 + wid) * 512);
        }
    }
    int aoff[2];
#pragma unroll
    for (int j = 0; j < 2; ++j) {
        int d = (j * 4 + wid) * 64 + lane;
        int o = d >> 3, u = d & 7;
        aoff[j] = (og * 64 + o) * 256 + ((u ^ (o & 7)) * 8);
    }
    auto stageA = [&](int s, int buf) {
        const ushort* base = wt + (size_t)(s >> 2) * 65536 + (s & 3) * 64;
#pragma unroll
        for (int j = 0; j < 2; ++j)
            gload_lds16(base + aoff[j], &As[buf][0][0] + (size_t)(j * 4 + wid) * 512);
    };
    stageA(0, 0);
    stageA(1, 1);
    __syncthreads();
    f32x4 acc[2][2];
#pragma unroll
    for (int mf = 0; mf < 2; ++mf)
#pragma unroll
        for (int nf = 0; nf < 2; ++nf) acc[mf][nf] = (f32x4){0.f, 0.f, 0.f, 0.f};
    const short8 zf = {};
    for (int s = 0; s < 36; ++s) {
        int tap = s >> 2, kh = s & 3;
        int dy = tap / 3 - 1, dx = tap % 3 - 1;
        const ushort* bp[2]; bool ok[2]; int lt7[2];
#pragma unroll
        for (int nf = 0; nf < 2; ++nf) {
            int n = tg * 64 + wn * 32 + nf * 16 + l16;
            int ny = (n >> 4) + dy, nx = (n & 15) + dx;
            ok[nf] = ((unsigned)ny < 16u) && ((unsigned)nx < 16u);
            int lrc = min(max(ny - ty0 + 1, 0), 5);
            int nxc = min(max(nx, 0), 15);
            int ltok = lrc * 16 + nxc;
            bp[nf] = &Bs[ltok][0];
            lt7[nf] = ltok & 7;
        }
#pragma unroll
        for (int kc = 0; kc < 2; ++kc) {
            int ua = kc * 4 + kq;
            int ub = kh * 8 + kc * 4 + kq;
            short8 af[2], bfr[2];
#pragma unroll
            for (int mf = 0; mf < 2; ++mf) {
                int o = wm * 32 + mf * 16 + l16;
                af[mf] = *(const short8*)(&As[s & 1][o][(ua ^ (o & 7)) * 8]);
            }
#pragma unroll
            for (int nf = 0; nf < 2; ++nf) {
                short8 v = *(const short8*)(bp[nf] + ((ub ^ lt7[nf]) * 8));
                bfr[nf] = ok[nf] ? v : zf;
            }
#pragma unroll
            for (int mf = 0; mf < 2; ++mf)
#pragma unroll
                for (int nf = 0; nf < 2; ++nf)
                    acc[mf][nf] = __builtin_amdgcn_mfma_f32_16x16x32_bf16(af[mf], bfr[nf], acc[mf][nf], 0, 0, 0);
        }
        __syncthreads();
        if (s + 2 < 36) stageA(s + 2, s & 1);
    }
    float ss[2][4];
#pragma unroll
    for (int mf = 0; mf < 2; ++mf)
#pragma unroll
        for (int r = 0; r < 4; ++r) ss[mf][r] = 0.f;
#pragma unroll
    for (int mf = 0; mf < 2; ++mf)
#pragma unroll
        for (int nf = 0; nf < 2; ++nf)
#pragma unroll
            for (int r = 0; r < 4; ++r) ss[mf][r] += acc[mf][nf][r] * acc[mf][nf][r];
#pragma unroll
    for (int mf = 0; mf < 2; ++mf)
#pragma unroll
        for (int r = 0; r < 4; ++r) {
#pragma unroll
            for (int off = 1; off < 16; off <<= 1) ss[mf][r] += __shfl_xor(ss[mf][r], off, 64);
        }
    if (l16 == 0) {
#pragma unroll
        for (int mf = 0; mf < 2; ++mf)
#pragma unroll
            for (int r = 0; r < 4; ++r)
                atomicAdd(&nrm[b * 256 + og * 64 + wm * 32 + mf * 16 + kq * 4 + r], ss[mf][r]);
    }
    ushort* ob = outp + (size_t)b * 65536;
#pragma unroll
    for (int mf = 0; mf < 2; ++mf)
#pragma unroll
        for (int nf = 0; nf < 2; ++nf) {
            int col = tg * 64 + wn * 32 + nf * 16 + l16;
#pragma unroll
            for (int r = 0; r < 4; ++r) {
                int row = og * 64 + wm * 32 + mf * 16 + kq * 4 + r;
                ob[(size_t)row * 256 + col] = f2bf(acc[mf][nf][r]);
            }
        }
}

// ---- attn via MFMA + norms + softmax; 64 blocks; attnT[d][c] bf16 ------------
__global__ void __launch_bounds__(512) attn_mfma(const ushort* __restrict__ qb,
                                                 const ushort* __restrict__ kTb,
                                                 const float* __restrict__ qnorm,
                                                 const float* __restrict__ knorm,
                                                 ushort* __restrict__ attnT) {
    int blk = blockIdx.x;
    int b = (blk & 7) + 8 * ((blk >> 3) & 1);
    int cg = blk >> 4;
    int tid = threadIdx.x, wid = tid >> 6, lane = tid & 63;
    int rw = wid & 3, chf = wid >> 2;
    int kq = lane >> 4, l16 = lane & 15;
    int c0w = cg * 64 + rw * 16;
    int lrow = rw * 16 + kq * 4;
    f32x4 acc[8];
#pragma unroll
    for (int nf = 0; nf < 8; ++nf) acc[nf] = (f32x4){0.f, 0.f, 0.f, 0.f};
    const ushort* qp = qb + (size_t)b * 65536;
    const ushort* kp = kTb + (size_t)b * 65536 + (size_t)(chf * 128) * 256;
    for (int kc = 0; kc < 8; ++kc) {
        short8 af = *(const short8*)(qp + (size_t)(c0w + l16) * 256 + kc * 32 + kq * 8);
#pragma unroll
        for (int nf = 0; nf < 8; ++nf) {
            short8 bf = *(const short8*)(kp + (size_t)(nf * 16 + l16) * 256 + kc * 32 + kq * 8);
            acc[nf] = __builtin_amdgcn_mfma_f32_16x16x32_bf16(af, bf, acc[nf], 0, 0, 0);
        }
    }
    float rq[4], rk[8];
#pragma unroll
    for (int r = 0; r < 4; ++r)
        rq[r] = rsqrtf(fmaxf(qnorm[b * 256 + c0w + kq * 4 + r], 1e-24f)) * 0.0625f;
#pragma unroll
    for (int nf = 0; nf < 8; ++nf)
        rk[nf] = rsqrtf(fmaxf(knorm[b * 256 + chf * 128 + nf * 16 + l16], 1e-24f));
#pragma unroll
    for (int nf = 0; nf < 8; ++nf)
#pragma unroll
        for (int r = 0; r < 4; ++r) acc[nf][r] *= rq[r] * rk[nf];
    __shared__ float red[64][2];
    float m4[4], s4[4];
#pragma unroll
    for (int r = 0; r < 4; ++r) {
        float m = -1e30f;
#pragma unroll
        for (int nf = 0; nf < 8; ++nf) m = fmaxf(m, acc[nf][r]);
#pragma unroll
        for (int off = 1; off < 16; off <<= 1) m = fmaxf(m, __shfl_xor(m, off, 64));
        m4[r] = m;
    }
    if (l16 == 0) {
#pragma unroll
        for (int r = 0; r < 4; ++r) red[lrow + r][chf] = m4[r];
    }
    __syncthreads();
#pragma unroll
    for (int r = 0; r < 4; ++r) m4[r] = fmaxf(red[lrow + r][0], red[lrow + r][1]);
    __syncthreads();
#pragma unroll
    for (int r = 0; r < 4; ++r) {
        float s = 0.f;
#pragma unroll
        for (int nf = 0; nf < 8; ++nf) {
            float ex = __expf(acc[nf][r] - m4[r]);
            acc[nf][r] = ex;
            s += ex;
        }
#pragma unroll
        for (int off = 1; off < 16; off <<= 1) s += __shfl_xor(s, off, 64);
        s4[r] = s;
    }
    if (l16 == 0) {
#pragma unroll
        for (int r = 0; r < 4; ++r) red[lrow + r][chf] = s4[r];
    }
    __syncthreads();
#pragma unroll
    for (int r = 0; r < 4; ++r) {
        float inv = 1.0f / (red[lrow + r][0] + red[lrow + r][1]);
#pragma unroll
        for (int nf = 0; nf < 8; ++nf) acc[nf][r] *= inv;
    }
    ushort* ap = attnT + (size_t)b * 65536;
#pragma unroll
    for (int nf = 0; nf < 8; ++nf) {
        int d = chf * 128 + nf * 16 + l16;
        short4v v;
#pragma unroll
        for (int r = 0; r < 4; ++r) v[r] = (short)f2bf(acc[nf][r]);
        *(short4v*)(ap + (size_t)d * 256 + c0w + kq * 4) = v;
    }
}

// ---- Mbf[b][o][d] = bf16( sum_c pbf[o,c] * attnT[d,c] ); 64 blocks -----------
__global__ void __launch_bounds__(512) mproj_mfma(const ushort* __restrict__ pbf,
                                                  const ushort* __restrict__ attnT,
                                                  ushort* __restrict__ Mbf) {
    int blk = blockIdx.x;
    int b = (blk & 7) + 8 * ((blk >> 3) & 1);
    int og = blk >> 4;
    int tid = threadIdx.x, wid = tid >> 6, lane = tid & 63;
    int rw = wid & 3, chf = wid >> 2;
    int kq = lane >> 4, l16 = lane & 15;
    int o0w = og * 64 + rw * 16;
    f32x4 acc[8];
#pragma unroll
    for (int nf = 0; nf < 8; ++nf) acc[nf] = (f32x4){0.f, 0.f, 0.f, 0.f};
    const ushort* ap = attnT + (size_t)b * 65536 + (size_t)(chf * 128) * 256;
    for (int kc = 0; kc < 8; ++kc) {
        short8 af = *(const short8*)(pbf + (size_t)(o0w + l16) * 256 + kc * 32 + kq * 8);
#pragma unroll
        for (int nf = 0; nf < 8; ++nf) {
            short8 bf = *(const short8*)(ap + (size_t)(nf * 16 + l16) * 256 + kc * 32 + kq * 8);
            acc[nf] = __builtin_amdgcn_mfma_f32_16x16x32_bf16(af, bf, acc[nf], 0, 0, 0);
        }
    }
    ushort* mb = Mbf + (size_t)b * 65536;
#pragma unroll
    for (int nf = 0; nf < 8; ++nf)
#pragma unroll
        for (int r = 0; r < 4; ++r)
            mb[(size_t)(o0w + kq * 4 + r) * 256 + chf * 128 + nf * 16 + l16] = f2bf(acc[nf][r]);
}

// ---- wbf[b][j][o][i] = bf16( sum_d Mbf[b,o,d] * vwT[j,i,d] ) via MFMA --------
__global__ void __launch_bounds__(512) weff_mfma(const ushort* __restrict__ Mbf,
                                                 const ushort* __restrict__ vwT,
                                                 ushort* __restrict__ wbf) {
    int blk = blockIdx.x;
    int i = blk >> 3;
    int b = (blk & 7) + 8 * (i >> 4);
    int j = i & 15;
    if (j >= 9) return;
    int tid = threadIdx.x;
    int wid = tid >> 6, lane = tid & 63;
    int wm = wid >> 1, wn = wid & 1;
    int kq = lane >> 4, l16 = lane & 15;
    f32x4 acc[4][8];
#pragma unroll
    for (int mf = 0; mf < 4; ++mf)
#pragma unroll
        for (int nf = 0; nf < 8; ++nf) acc[mf][nf] = (f32x4){0.f, 0.f, 0.f, 0.f};
    const ushort* abase = Mbf + (size_t)b * 65536 + (size_t)(wm * 64 + l16) * 256 + kq * 8;
    const ushort* bbase = vwT + (size_t)(j * 256 + wn * 128 + l16) * 256 + kq * 8;
    for (int kc = 0; kc < 8; ++kc) {
        int d0 = kc * 32;
        short8 af[4], bfr[8];
#pragma unroll
        for (int mf = 0; mf < 4; ++mf) af[mf] = *(const short8*)(abase + mf * 16 * 256 + d0);
#pragma unroll
        for (int nf = 0; nf < 8; ++nf) bfr[nf] = *(const short8*)(bbase + nf * 16 * 256 + d0);
#pragma unroll
        for (int mf = 0; mf < 4; ++mf)
#pragma unroll
            for (int nf = 0; nf < 8; ++nf)
                acc[mf][nf] = __builtin_amdgcn_mfma_f32_16x16x32_bf16(af[mf], bfr[nf], acc[mf][nf], 0, 0, 0);
    }
    ushort* wout = wbf + ((size_t)(b * 9 + j)) * 65536;
#pragma unroll
    for (int mf = 0; mf < 4; ++mf) {
        int o = wm * 64 + mf * 16 + kq * 4;
#pragma unroll
        for (int nf = 0; nf < 8; ++nf) {
            int ic = wn * 128 + nf * 16 + l16;
#pragma unroll
            for (int r = 0; r < 4; ++r)
                wout[(size_t)(o + r) * 256 + ic] = f2bf(acc[mf][nf][r]);
        }
    }
}

// ---- big conv v5: 4-row tile, 4x4 wave frag (MFMA-bound), LDS A dbuf ---------
// grid 512 = b(XCD-bij 16) x pt(16: 4-row tiles) x oh(2); 8 waves: wr(4) x wo(2)
__global__ void __launch_bounds__(512, 4) bigconv_mfma(const float* __restrict__ e,
                                                       const ushort* __restrict__ wbf,
                                                       float* __restrict__ out) {
    int blk = blockIdx.x;
    int ibf = blk >> 3;
    int b = (blk & 7) + 8 * (ibf >> 5);
    int rem = ibf & 31;
    int pt = rem >> 1, oh = rem & 1;
    int y0 = pt * 4;
    int tid = threadIdx.x, wid = tid >> 6, lane = tid & 63;
    int wr = wid >> 1, wo = wid & 1;
    int kq = lane >> 4, l16 = lane & 15;
    __shared__ ushort Bs[6][64][64];   // 48 KB: rows y0-1..y0+4
    __shared__ ushort As[2][128][64];  // 32 KB dbuf
    f32x4 acc[4][4];
#pragma unroll
    for (int mf = 0; mf < 4; ++mf)
#pragma unroll
        for (int nf = 0; nf < 4; ++nf) acc[mf][nf] = (f32x4){0.f, 0.f, 0.f, 0.f};
    const float* eb = e + (size_t)b * NC * NPIX;
    const ushort* wb = wbf + (size_t)b * 589824;
    const short8 zf = {};
    // B-stage roles: 384 active threads = 32 ch-pairs x 6 rows x 2 px-halves
    int c2 = tid & 31, rr = tid >> 5;
    int sr = rr >> 1, sq = rr & 1;
    bool bstage = (rr < 12);
    int syc = min(max(y0 - 1 + sr, 0), 63);
    // A-stage invariants
    int ao[2], asd[2];
#pragma unroll
    for (int j = 0; j < 2; ++j) {
        int du = (j * 8 + wid) * 64 + lane;
        ao[j] = du >> 3;
        asd[j] = (lane & 7) ^ (ao[j] & 7);
    }

    for (int ci = 0; ci < 4; ++ci) {
        __syncthreads();
        // ---- stage B: 6 rows x 64 px x 64 ch, fused NHWC+swizzle, 2 phases ----
        if (bstage) {
            const float* s0 = eb + ((size_t)(ci * 64 + 2 * c2) * 64 + syc) * 64 + sq * 32;
            const float* s1 = s0 + NPIX;
            uint* bsrow = (uint*)&Bs[sr][0][0];
#pragma unroll
            for (int h = 0; h < 2; ++h) {
                float4 va[4], vb[4];
#pragma unroll
                for (int q = 0; q < 4; ++q) va[q] = *(const float4*)(s0 + h * 16 + q * 4);
#pragma unroll
                for (int q = 0; q < 4; ++q) vb[q] = *(const float4*)(s1 + h * 16 + q * 4);
#pragma unroll
                for (int q = 0; q < 4; ++q) {
#pragma unroll
                    for (int m2 = 0; m2 < 4; ++m2) {
                        int px = sq * 32 + h * 16 + q * 4 + m2;
                        float f0 = ((const float*)&va[q])[m2];
                        float f1 = ((const float*)&vb[q])[m2];
                        uint pk = (uint)f2bf(f0) | ((uint)f2bf(f1) << 16);
                        int s = (c2 >> 2) ^ (px & 7);
                        bsrow[px * 32 + s * 4 + (c2 & 3)] = pk;
                    }
                }
            }
        }
        // ---- stage A(tap 0) into buf 0 ----
        {
#pragma unroll
            for (int j = 0; j < 2; ++j) {
                const ushort* src = wb + (size_t)(oh * 128 + ao[j]) * 256 + ci * 64 + asd[j] * 8;
                gload_lds16(src, &As[0][0][0] + (size_t)(j * 8 + wid) * 512);
            }
        }
        __syncthreads();
        int cur = 0;
        for (int tap = 0; tap < 9; ++tap) {
            if (tap < 8) {
#pragma unroll
                for (int j = 0; j < 2; ++j) {
                    const ushort* src = wb + (size_t)(tap + 1) * 65536 +
                                        (size_t)(oh * 128 + ao[j]) * 256 + ci * 64 + asd[j] * 8;
                    gload_lds16(src, &As[cur ^ 1][0][0] + (size_t)(j * 8 + wid) * 512);
                }
            }
            {
                int dy = tap / 3 - 1, dx = tap % 3 - 1;
                int rl = wr + dy + 1;
                bool rowok = (unsigned)(y0 + wr + dy) < 64u;
                const ushort* bp[4]; bool ok[4]; int p7[4];
#pragma unroll
                for (int nf = 0; nf < 4; ++nf) {
                    int pxr = nf * 16 + l16 + dx;
                    ok[nf] = rowok && ((unsigned)pxr < 64u);
                    int pxc = min(max(pxr, 0), 63);
                    bp[nf] = &Bs[rl][pxc][0];
                    p7[nf] = pxc & 7;
                }
#pragma unroll
                for (int kc = 0; kc < 2; ++kc) {
                    int sd = kc * 4 + kq;
                    short8 af[4];
#pragma unroll
                    for (int mf = 0; mf < 4; ++mf) {
                        int o = wo * 64 + mf * 16 + l16;
                        af[mf] = *(const short8*)(&As[cur][o][(sd ^ (o & 7)) * 8]);
                    }
                    short8 bfr[4];
#pragma unroll
                    for (int nf = 0; nf < 4; ++nf) {
                        short8 v = *(const short8*)(bp[nf] + (sd ^ p7[nf]) * 8);
                        bfr[nf] = ok[nf] ? v : zf;
                    }
#pragma unroll
                    for (int mf = 0; mf < 4; ++mf)
#pragma unroll
                        for (int nf = 0; nf < 4; ++nf)
                            acc[mf][nf] = __builtin_amdgcn_mfma_f32_16x16x32_bf16(af[mf], bfr[nf], acc[mf][nf], 0, 0, 0);
                }
            }
            __syncthreads();
            cur ^= 1;
        }
    }
    // ---- epilogue: + residual ----
    int prow = y0 + wr;
    float* ob = out + (size_t)b * NC * NPIX;
#pragma unroll
    for (int mf = 0; mf < 4; ++mf) {
        int o = oh * 128 + wo * 64 + mf * 16 + kq * 4;
#pragma unroll
        for (int nf = 0; nf < 4; ++nf) {
            int p = prow * 64 + nf * 16 + l16;
#pragma unroll
            for (int r = 0; r < 4; ++r) {
                size_t idx = (size_t)(o + r) * NPIX + p;
                ob[idx] = acc[mf][nf][r] + eb[idx];
            }
        }
    }
}

extern "C" void kernel_launch(void* const* d_in, const int* in_sizes, int n_in,
                              void* d_out, int out_size, void* d_ws, size_t ws_size,
                              hipStream_t stream) {
    const float* e   = (const float*)d_in[0];
    const float* pam = (const float*)d_in[1];
    const float* qw  = (const float*)d_in[2];
    const float* kw  = (const float*)d_in[3];
    const float* vw  = (const float*)d_in[4];
    const float* pw  = (const float*)d_in[5];
    float* out = (float*)d_out;
    float* ws  = (float*)d_ws;

    ushort* wbf  = (ushort*)ws;                      // 9,437,184 ushorts (18.9MB)
    float*  S    = ws + 4718592;
    ushort* maxeT = (ushort*)S;
    ushort* pamT  = (ushort*)(S + 524288);
    ushort* wqT   = (ushort*)(S + 1048576);
    ushort* wkT   = (ushort*)(S + 1343488);
    ushort* pbf   = (ushort*)(S + 1638400);
    ushort* vwT   = (ushort*)(S + 1671168);
    float*  qnorm = S + 1966080;
    float*  knorm = S + 1970176;
    ushort* qb    = (ushort*)ws;
    ushort* kTb   = (ushort*)(ws + 524288);
    ushort* attnT = maxeT;
    ushort* Mbf   = pamT;

    prep_k<<<1873, 256, 0, stream>>>(e, pam, qw, kw, vw, pw,
                                     maxeT, pamT, wqT, wkT, pbf, vwT, qnorm, knorm);
    conv16_mfma<<<512, 256, 0, stream>>>(maxeT, pamT, wqT, wkT, qb, kTb, qnorm, knorm);
    attn_mfma<<<64, 512, 0, stream>>>(qb, kTb, qnorm, knorm, attnT);
    mproj_mfma<<<64, 512, 0, stream>>>(pbf, attnT, Mbf);
    weff_mfma<<<256, 512, 0, stream>>>(Mbf, vwT, wbf);
    bigconv_mfma<<<512, 512, 0, stream>>>(e, wbf, out);
}